// Round 2
// baseline (343.396 us; speedup 1.0000x reference)
//
#include <hip/hip_runtime.h>
#include <stdint.h>

#define N_NODES 1024
#define NCLS 10
#define KDIM 131072  // 1024*128

typedef unsigned short u16;
typedef __bf16 bf16x8 __attribute__((ext_vector_type(8)));
typedef float f32x4 __attribute__((ext_vector_type(4)));

__device__ __forceinline__ float b2f_lo(uint32_t u) {
  union { float f; uint32_t u; } v; v.u = u << 16; return v.f;
}
__device__ __forceinline__ float b2f_hi(uint32_t u) {
  union { float f; uint32_t u; } v; v.u = u & 0xFFFF0000u; return v.f;
}
__device__ __forceinline__ u16 f2b(float f) {
  union { float f; uint32_t u; } v; v.f = f;
  uint32_t r = v.u + 0x7FFF + ((v.u >> 16) & 1);
  return (u16)(r >> 16);
}
__device__ __forceinline__ uint32_t pkbf(float a, float b) {
#if __has_builtin(__builtin_amdgcn_cvt_pk_bf16_f32)
  typedef __bf16 bf2 __attribute__((ext_vector_type(2)));
  bf2 r = __builtin_amdgcn_cvt_pk_bf16_f32(a, b);
  union { bf2 v; uint32_t u; } c; c.v = r; return c.u;
#else
  union { float f; uint32_t u; } va, vb; va.f = a; vb.f = b;
  uint32_t ra = (va.u + 0x7FFF + ((va.u >> 16) & 1)) >> 16;
  uint32_t rb = (vb.u + 0x7FFF + ((vb.u >> 16) & 1)) & 0xFFFF0000u;
  return ra | rb;
#endif
}

__device__ __forceinline__ void async_copy16(const u16* g, u16* l) {
  __builtin_amdgcn_global_load_lds(
      (const __attribute__((address_space(1))) void*)g,
      (__attribute__((address_space(3))) void*)l, 16, 0, 0);
}

// accumulate 8 bf16 (one uint4) scaled by c into float2 acc[4]
__device__ __forceinline__ void agg8(uint4 v, float c, float2* acc) {
  const uint32_t* u = (const uint32_t*)&v;
#pragma unroll
  for (int e = 0; e < 4; e++) {
    acc[e].x += c * b2f_lo(u[e]);
    acc[e].y += c * b2f_hi(u[e]);
  }
}

// ---------------- prep kernels ----------------
__global__ __launch_bounds__(256) void cvt_w_kernel(const float* __restrict__ w,
                                                    u16* __restrict__ o, int n) {
  int i = blockIdx.x * 256 + threadIdx.x;
  if (i < n) o[i] = f2b(w[i]);
}

__global__ __launch_bounds__(256) void prep_wc_kernel(const float* __restrict__ wc,
                                                      u16* __restrict__ o) {
  int i = blockIdx.x * 256 + threadIdx.x;  // 16*KDIM total
  int row = i >> 17;
  int col = i & (KDIM - 1);
  o[i] = (row < NCLS) ? f2b(wc[row * KDIM + col]) : (u16)0;
}

__global__ __launch_bounds__(256) void prep_tab_kernel(const float* __restrict__ adj,
                                                       int* __restrict__ nbi,
                                                       float* __restrict__ nbc,
                                                       float* __restrict__ r) {
  int m = blockIdx.x * 256 + threadIdx.x;
  if (m >= N_NODES) return;
  int i = m >> 5, j = m & 31;
  const float* arow = adj + (size_t)m * N_NODES;
  int n[5]; float c[5];
  n[0] = m;                      c[0] = arow[m];
  n[1] = (i > 0)  ? m - 32 : m;  c[1] = (i > 0)  ? arow[m - 32] : 0.f;
  n[2] = (i < 31) ? m + 32 : m;  c[2] = (i < 31) ? arow[m + 32] : 0.f;
  n[3] = (j > 0)  ? m - 1  : m;  c[3] = (j > 0)  ? arow[m - 1]  : 0.f;
  n[4] = (j < 31) ? m + 1  : m;  c[4] = (j < 31) ? arow[m + 1]  : 0.f;
  float s = 0.f;
#pragma unroll
  for (int t = 0; t < 5; t++) { nbi[m * 5 + t] = n[t]; nbc[m * 5 + t] = c[t]; s += c[t]; }
  r[m] = s;
}

// pack W1 [256,3] + b1 [256] -> [256][4] f32 (w0,w1,w2,b)
__global__ __launch_bounds__(256) void prep_w1_kernel(const float* __restrict__ W1,
                                                      const float* __restrict__ b1,
                                                      float* __restrict__ o) {
  int c = threadIdx.x;
  float4 v;
  v.x = W1[c * 3];
  v.y = W1[c * 3 + 1];
  v.z = W1[c * 3 + 2];
  v.w = b1[c];
  ((float4*)o)[c] = v;
}

__global__ __launch_bounds__(256) void outinit_kernel(const float* __restrict__ bc,
                                                      float* __restrict__ out) {
  int idx = blockIdx.x * 256 + threadIdx.x;
  if (idx < 256 * NCLS) out[idx] = bc[idx % NCLS];
}

// ---------------- fused layer1+agg+layer2: h2 = relu((A.h1) W2^T + r.b2) ----------------
// Two-phase A-production per 64-wide K-chunk:
//   Phase1: h1[halo row][ch] computed ONCE (no 5x stencil redundancy) into
//           h1c LDS (bf16, xor-octet swizzled), w1 coeffs held in registers.
//   Phase2: 5-point aggregation h1c -> As (xor-octet swizzled, same po
//           swizzle as Bs on the MFMA read side).
// Phase1(kq+1) is placed in the MFMA(kq) phase so its latency hides under
// the matrix pipe. LDS 79 KB -> 2 blocks/CU.
__global__ __launch_bounds__(256, 2) void l12mm_kernel(
    const float* __restrict__ x,     // [chunk,3,1024]
    const float* __restrict__ w1p,   // [256][4] f32: w0,w1,w2,b1
    const u16* __restrict__ W2b,     // [256,256] bf16
    const float* __restrict__ b2,    // [256]
    const float* __restrict__ r,     // [1024]
    const int* __restrict__ nbi, const float* __restrict__ nbc,
    u16* __restrict__ C)             // h2 [M,256] bf16
{
  const int K = 256;
  __shared__ u16 As[128 * 64];       // 16 KB (swizzled)
  __shared__ u16 Bs[256 * 64];       // 32 KB (glds source-swizzled)
  __shared__ u16 h1c[192 * 64];      // 24 KB (swizzled)
  __shared__ float gxs[192][4];      // 3 KB  (gx0,gx1,gx2,rn) per halo node
  __shared__ float w1s[256][4];      // 4 KB

  int m0 = blockIdx.x * 128;
  int b = m0 >> 10;
  int node0 = m0 & 1023;
  int e0 = node0 - 32;
  int tid = threadIdx.x;
  int w = tid >> 6, l = tid & 63;
  int wm = w >> 1, wn = w & 1;

  // B staging (proven swizzled-glds layout)
  int r8 = l >> 3, oct = l & 7;
  int so = (oct ^ r8) << 3;
  const u16* gb0 = W2b + (size_t)(w * 64 + r8) * K + so;

#define L12_ISSUEB(kq) \
  _Pragma("unroll") for (int q = 0; q < 8; q++) \
    async_copy16(gb0 + (size_t)q * 8 * K + (kq) * 64, &Bs[(w * 64 + q * 8) * 64]);

  L12_ISSUEB(0);

  // prologue: W1|b1 table + halo gx
  *(float4*)&w1s[tid][0] = ((const float4*)w1p)[tid];
  if (tid < 192) {
    int n = e0 + tid;
    float4 gv = {0.f, 0.f, 0.f, 0.f};
    if (n >= 0 && n < N_NODES) {
      const float* xb = x + (size_t)b * 3072;
      float g0 = 0.f, g1 = 0.f, g2 = 0.f;
#pragma unroll
      for (int t = 0; t < 5; t++) {
        int nb = nbi[n * 5 + t]; float cv = nbc[n * 5 + t];
        g0 += cv * xb[nb];
        g1 += cv * xb[1024 + nb];
        g2 += cv * xb[2048 + nb];
      }
      gv.x = g0; gv.y = g1; gv.z = g2; gv.w = r[n];
    }
    *(float4*)&gxs[tid][0] = gv;
  }

  // phase-1 assignment: thread -> (8-ch group cg, rows rb, rb+32, ... rb+160)
  int cg = tid & 7;
  int rb = tid >> 3;                 // 0..31
  int po1 = (cg ^ (rb & 7)) << 3;    // physical octet offset in h1c row

#define L12_PHASE1(kq_) { \
    float4 q_[8]; \
    _Pragma("unroll") for (int j = 0; j < 8; j++) \
      q_[j] = *(const float4*)&w1s[(kq_) * 64 + cg * 8 + j][0]; \
    _Pragma("unroll") for (int i = 0; i < 6; i++) { \
      int row_ = rb + 32 * i; \
      float4 g_ = *(const float4*)&gxs[row_][0]; \
      uint32_t pk_[4]; \
      _Pragma("unroll") for (int j = 0; j < 8; j += 2) { \
        float h0_ = fmaxf(fmaf(g_.x, q_[j].x, fmaf(g_.y, q_[j].y, fmaf(g_.z, q_[j].z, g_.w * q_[j].w))), 0.f); \
        float h1_ = fmaxf(fmaf(g_.x, q_[j+1].x, fmaf(g_.y, q_[j+1].y, fmaf(g_.z, q_[j+1].z, g_.w * q_[j+1].w))), 0.f); \
        pk_[j >> 1] = pkbf(h0_, h1_); \
      } \
      *(uint4*)&h1c[row_ * 64 + po1] = *(uint4*)pk_; \
    } }

  // phase-2 assignment: thread -> (out row arow, 32-ch half h4*8)
  int arow = tid >> 1;
  int h4 = (tid & 1) << 2;           // logical octet base 0/4
  int node = node0 + arow;
  const u16* bp5[5]; int sw5[5]; float cf5[5];
#pragma unroll
  for (int t = 0; t < 5; t++) {
    int idx = nbi[node * 5 + t] - e0;     // always in [0,192)
    bp5[t] = h1c + idx * 64;
    sw5[t] = idx & 7;
    cf5[t] = nbc[node * 5 + t];
  }
  u16* adst = As + arow * 64;
  int asw = arow & 7;

#define L12_PHASE2() \
  _Pragma("unroll") for (int q = 0; q < 4; q++) { \
    int lo_ = h4 + q; \
    uint4 Lq_[5]; \
    _Pragma("unroll") for (int t = 0; t < 5; t++) \
      Lq_[t] = *(const uint4*)(bp5[t] + ((lo_ ^ sw5[t]) << 3)); \
    float2 a2_[4] = {}; \
    _Pragma("unroll") for (int t = 0; t < 5; t++) agg8(Lq_[t], cf5[t], a2_); \
    uint4 o_; \
    o_.x = pkbf(a2_[0].x, a2_[0].y); o_.y = pkbf(a2_[1].x, a2_[1].y); \
    o_.z = pkbf(a2_[2].x, a2_[2].y); o_.w = pkbf(a2_[3].x, a2_[3].y); \
    *(uint4*)(adst + ((lo_ ^ asw) << 3)) = o_; \
  }

  __syncthreads();      // gxs + w1s ready
  L12_PHASE1(0);

  f32x4 acc[4][8] = {};
  int lrow = l & 15, lq = l >> 4;
  int s2 = lrow & 7;

#pragma unroll
  for (int kq = 0; kq < 4; kq++) {
    __syncthreads();            // (A) h1c(kq) visible; MFMA(kq-1) done (As/Bs free)
    if (kq) L12_ISSUEB(kq);     // W2 chunk kq in flight under phase2
    L12_PHASE2();               // h1c(kq) -> As
    __syncthreads();            // (B) As ready; Bs(kq) drained
    if (kq < 3) L12_PHASE1(kq + 1);   // hides under MFMA below

    const u16* pa = &As[(wm * 64 + lrow) * 64];
    const u16* pb = &Bs[(wn * 128 + lrow) * 64];
#pragma unroll
    for (int kh = 0; kh < 2; kh++) {
      int po = (((kh << 2) | lq) ^ s2) << 3;   // physical octet offset (A and B)
      bf16x8 af[4], bf[8];
#pragma unroll
      for (int t = 0; t < 4; t++)
        af[t] = *(const bf16x8*)(pa + t * 16 * 64 + po);
#pragma unroll
      for (int t = 0; t < 8; t++)
        bf[t] = *(const bf16x8*)(pb + t * 16 * 64 + po);
#pragma unroll
      for (int mt = 0; mt < 4; mt++)
#pragma unroll
        for (int nt = 0; nt < 8; nt++)
          acc[mt][nt] = __builtin_amdgcn_mfma_f32_16x16x32_bf16(af[mt], bf[nt], acc[mt][nt], 0, 0, 0);
    }
  }
#undef L12_ISSUEB
#undef L12_PHASE1
#undef L12_PHASE2

#pragma unroll
  for (int mt = 0; mt < 4; mt++)
#pragma unroll
    for (int nt = 0; nt < 8; nt++) {
      f32x4 v = acc[mt][nt];
      int col = wn * 128 + nt * 16 + lrow;
      float bs = b2[col];
#pragma unroll
      for (int i2 = 0; i2 < 4; i2++) {
        int row = m0 + wm * 64 + mt * 16 + lq * 4 + i2;
        float val = v[i2] + r[row & 1023] * bs;
        C[(size_t)row * 256 + col] = f2b(fmaxf(val, 0.f));
      }
    }
}

// ---------------- mm3agg: h3 = relu((A h2) W3^T + r.b3) ----------------
__global__ __launch_bounds__(256, 2) void mm3agg_kernel(
    const u16* __restrict__ H,      // h2 [chunk*1024, 256]
    const u16* __restrict__ W,      // W3b [128, 256]
    const float* __restrict__ bias, const float* __restrict__ r,
    const int* __restrict__ nbi, const float* __restrict__ nbc,
    u16* __restrict__ C)            // h3 [chunk*1024, 128]
{
  const int K = 256, N = 128;
  const int AST = 72;               // padded A row stride (elements)
  __shared__ u16 As[2][128 * AST];  // 2x18 KB
  __shared__ u16 Bs[2][128 * 64];   // 2x16 KB
  int m0 = blockIdx.x * 128;
  int tid = threadIdx.x;
  int w = tid >> 6, l = tid & 63;
  int wm = w >> 1, wn = w & 1;

  // aggregation: thread -> (row = tid/2, 32-col half of each 64-k chunk)
  int arow = tid >> 1;
  int acol = (tid & 1) * 32;
  int pg = m0 + arow;
  int node = pg & 1023;
  const u16* hb = H + ((size_t)(pg >> 10) << 10) * 256 + acol;
  const u16* nbp[5]; float cf[5];
#pragma unroll
  for (int j = 0; j < 5; j++) {
    nbp[j] = hb + (size_t)nbi[node * 5 + j] * 256;
    cf[j] = nbc[node * 5 + j];
  }

  // B staging
  int r8 = l >> 3, oct = l & 7;
  int so = (oct ^ r8) << 3;
  const u16* gb0 = W + (size_t)(w * 32 + r8) * K + so;

#define M3_ISSUEB(kq, buf) \
  _Pragma("unroll") for (int q = 0; q < 4; q++) \
    async_copy16(gb0 + (size_t)q * 8 * K + (kq) * 64, &Bs[buf][(w * 32 + q * 8) * 64]);

#define M3_LOADA(kq) \
  _Pragma("unroll") for (int j = 0; j < 5; j++) \
    _Pragma("unroll") for (int q = 0; q < 4; q++) \
      L[j][q] = *(const uint4*)(nbp[j] + (kq) * 64 + q * 8);

#define M3_AGGSTORE(buf) { \
  u16* dst = &As[buf][arow * AST + acol]; \
  _Pragma("unroll") for (int q = 0; q < 4; q++) { \
    float2 acc2[4] = {}; \
    _Pragma("unroll") for (int j = 0; j < 5; j++) agg8(L[j][q], cf[j], acc2); \
    uint4 o; \
    o.x = pkbf(acc2[0].x, acc2[0].y); o.y = pkbf(acc2[1].x, acc2[1].y); \
    o.z = pkbf(acc2[2].x, acc2[2].y); o.w = pkbf(acc2[3].x, acc2[3].y); \
    *(uint4*)(dst + q * 8) = o; \
  } }

  uint4 L[5][4];
  M3_ISSUEB(0, 0);
  M3_LOADA(0);
  M3_AGGSTORE(0);

  f32x4 acc[4][4] = {};
  int lrow = l & 15, lq = l >> 4;
  int s = lrow & 7;

#pragma unroll
  for (int kq = 0; kq < 4; kq++) {
    int buf = kq & 1;
    __syncthreads();
    if (kq < 3) {
      M3_ISSUEB(kq + 1, buf ^ 1);
      M3_LOADA(kq + 1);               // in flight during MFMA below
    }
    const u16* pa = &As[buf][(wm * 64 + lrow) * AST];
    const u16* pb = &Bs[buf][(wn * 64 + lrow) * 64];
#pragma unroll
    for (int kh = 0; kh < 2; kh++) {
      int po = (((kh << 2) | lq) ^ s) << 3;
      bf16x8 af[4], bf[4];
#pragma unroll
      for (int t = 0; t < 4; t++) {
        af[t] = *(const bf16x8*)(pa + t * 16 * AST + kh * 32 + lq * 8);
        bf[t] = *(const bf16x8*)(pb + t * 16 * 64 + po);
      }
#pragma unroll
      for (int mt = 0; mt < 4; mt++)
#pragma unroll
        for (int nt = 0; nt < 4; nt++)
          acc[mt][nt] = __builtin_amdgcn_mfma_f32_16x16x32_bf16(af[mt], bf[nt], acc[mt][nt], 0, 0, 0);
    }
    if (kq < 3) M3_AGGSTORE(buf ^ 1);
  }
#undef M3_ISSUEB
#undef M3_LOADA
#undef M3_AGGSTORE

#pragma unroll
  for (int mt = 0; mt < 4; mt++)
#pragma unroll
    for (int nt = 0; nt < 4; nt++) {
      f32x4 v = acc[mt][nt];
      int col = wn * 64 + nt * 16 + lrow;
      float bs = bias[col];
#pragma unroll
      for (int i2 = 0; i2 < 4; i2++) {
        int row = m0 + wm * 64 + mt * 16 + lq * 4 + i2;
        float val = v[i2] + r[row & 1023] * bs;
        C[(size_t)row * N + col] = f2b(fmaxf(val, 0.f));
      }
    }
}

// ---------------- classifier ----------------
__global__ __launch_bounds__(256) void cls_kernel(
    const u16* __restrict__ h3,   // [chunk, KDIM] bf16
    const u16* __restrict__ Wcb,  // [16, KDIM] bf16 (rows 10..15 zero)
    float* __restrict__ out,      // [256, 10]
    int b0)
{
  int mt = blockIdx.x;
  int split = blockIdx.y;
  int w = threadIdx.x >> 6, l = threadIdx.x & 63;
  int lrow = l & 15, lq = l >> 4;
  f32x4 acc = {};
  int kbase = split * 4096 + w * 1024;
  const u16* pa = h3 + (size_t)(mt * 16 + lrow) * KDIM + kbase + lq * 8;
  const u16* pb = Wcb + (size_t)lrow * KDIM + kbase + lq * 8;
#pragma unroll 4
  for (int kk = 0; kk < 1024; kk += 32) {
    bf16x8 a = *(const bf16x8*)(pa + kk);
    bf16x8 b = *(const bf16x8*)(pb + kk);
    acc = __builtin_amdgcn_mfma_f32_16x16x32_bf16(a, b, acc, 0, 0, 0);
  }
  if (lrow < NCLS) {
#pragma unroll
    for (int i2 = 0; i2 < 4; i2++) {
      int b = b0 + mt * 16 + lq * 4 + i2;
      atomicAdd(&out[b * NCLS + lrow], acc[i2]);
    }
  }
}

extern "C" void kernel_launch(void* const* d_in, const int* in_sizes, int n_in,
                              void* d_out, int out_size, void* d_ws, size_t ws_size,
                              hipStream_t stream) {
  const float* x   = (const float*)d_in[0];
  const float* W1  = (const float*)d_in[1];
  const float* b1  = (const float*)d_in[2];
  const float* W2  = (const float*)d_in[3];
  const float* b2  = (const float*)d_in[4];
  const float* W3  = (const float*)d_in[5];
  const float* b3  = (const float*)d_in[6];
  const float* Wc  = (const float*)d_in[7];
  const float* bc  = (const float*)d_in[8];
  const float* adj = (const float*)d_in[9];
  float* out = (float*)d_out;
  const int B = 256;

  uint8_t* ws = (uint8_t*)d_ws;
  u16* W2b = (u16*)ws;  ws += (size_t)256 * 256 * 2;
  u16* W3b = (u16*)ws;  ws += (size_t)128 * 256 * 2;
  u16* Wcb = (u16*)ws;  ws += (size_t)16 * KDIM * 2;
  float* rr  = (float*)ws; ws += 1024 * 4;
  int*   nbi = (int*)ws;   ws += 1024 * 5 * 4;
  float* nbc = (float*)ws; ws += 1024 * 5 * 4;
  float* w1p = (float*)ws; ws += 256 * 4 * 4;
  uintptr_t al = ((uintptr_t)ws + 255) & ~(uintptr_t)255;
  ws = (uint8_t*)al;
  size_t used = (size_t)(ws - (uint8_t*)d_ws);
  size_t avail = (ws_size > used) ? ws_size - used : 0;
  int chunk = 256;
  while (chunk > 32 && (size_t)chunk * 1024 * 256 * 2 * 2 > avail) chunk >>= 1;
  u16* bufA = (u16*)ws;
  u16* bufB = bufA + (size_t)chunk * 1024 * 256;

  cvt_w_kernel<<<256, 256, 0, stream>>>(W2, W2b, 256 * 256);
  cvt_w_kernel<<<128, 256, 0, stream>>>(W3, W3b, 128 * 256);
  prep_wc_kernel<<<(16 * KDIM) / 256, 256, 0, stream>>>(Wc, Wcb);
  prep_tab_kernel<<<4, 256, 0, stream>>>(adj, nbi, nbc, rr);
  prep_w1_kernel<<<1, 256, 0, stream>>>(W1, b1, w1p);
  outinit_kernel<<<(256 * NCLS + 255) / 256, 256, 0, stream>>>(bc, out);

  for (int b0 = 0; b0 < B; b0 += chunk) {
    const float* xb = x + (size_t)b0 * 3 * 1024;
    int M = chunk * 1024;
    // h2 = relu((A.h1) W2^T + r.b2) fused from x -> bufA
    l12mm_kernel<<<M / 128, 256, 0, stream>>>(xb, w1p, W2b, b2, rr, nbi, nbc, bufA);
    // h3 = relu((A.h2) W3^T + r.b3) -> bufB
    mm3agg_kernel<<<M / 128, 256, 0, stream>>>(bufA, W3b, b3, rr, nbi, nbc, bufB);
    dim3 gc(chunk / 16, 32);
    cls_kernel<<<gc, 256, 0, stream>>>(bufB, Wcb, out, b0);
  }
}

// Round 3
// 331.645 us; speedup vs baseline: 1.0354x; 1.0354x over previous
//
#include <hip/hip_runtime.h>
#include <stdint.h>

#define N_NODES 1024
#define NCLS 10
#define KDIM 131072  // 1024*128

typedef unsigned short u16;
typedef __bf16 bf16x8 __attribute__((ext_vector_type(8)));
typedef float f32x4 __attribute__((ext_vector_type(4)));

__device__ __forceinline__ float b2f_lo(uint32_t u) {
  union { float f; uint32_t u; } v; v.u = u << 16; return v.f;
}
__device__ __forceinline__ float b2f_hi(uint32_t u) {
  union { float f; uint32_t u; } v; v.u = u & 0xFFFF0000u; return v.f;
}
__device__ __forceinline__ u16 f2b(float f) {
  union { float f; uint32_t u; } v; v.f = f;
  uint32_t r = v.u + 0x7FFF + ((v.u >> 16) & 1);
  return (u16)(r >> 16);
}
__device__ __forceinline__ uint32_t pkbf(float a, float b) {
#if __has_builtin(__builtin_amdgcn_cvt_pk_bf16_f32)
  typedef __bf16 bf2 __attribute__((ext_vector_type(2)));
  bf2 r = __builtin_amdgcn_cvt_pk_bf16_f32(a, b);
  union { bf2 v; uint32_t u; } c; c.v = r; return c.u;
#else
  union { float f; uint32_t u; } va, vb; va.f = a; vb.f = b;
  uint32_t ra = (va.u + 0x7FFF + ((va.u >> 16) & 1)) >> 16;
  uint32_t rb = (vb.u + 0x7FFF + ((vb.u >> 16) & 1)) & 0xFFFF0000u;
  return ra | rb;
#endif
}

__device__ __forceinline__ void async_copy16(const u16* g, u16* l) {
  __builtin_amdgcn_global_load_lds(
      (const __attribute__((address_space(1))) void*)g,
      (__attribute__((address_space(3))) void*)l, 16, 0, 0);
}

// accumulate 8 bf16 (one uint4) scaled by c into float2 acc[4]
__device__ __forceinline__ void agg8(uint4 v, float c, float2* acc) {
  const uint32_t* u = (const uint32_t*)&v;
#pragma unroll
  for (int e = 0; e < 4; e++) {
    acc[e].x += c * b2f_lo(u[e]);
    acc[e].y += c * b2f_hi(u[e]);
  }
}

// ---------------- prep kernels ----------------
__global__ __launch_bounds__(256) void cvt_w_kernel(const float* __restrict__ w,
                                                    u16* __restrict__ o, int n) {
  int i = blockIdx.x * 256 + threadIdx.x;
  if (i < n) o[i] = f2b(w[i]);
}

__global__ __launch_bounds__(256) void prep_wc_kernel(const float* __restrict__ wc,
                                                      u16* __restrict__ o) {
  int i = blockIdx.x * 256 + threadIdx.x;  // 16*KDIM total
  int row = i >> 17;
  int col = i & (KDIM - 1);
  o[i] = (row < NCLS) ? f2b(wc[row * KDIM + col]) : (u16)0;
}

__global__ __launch_bounds__(256) void prep_tab_kernel(const float* __restrict__ adj,
                                                       int* __restrict__ nbi,
                                                       float* __restrict__ nbc,
                                                       float* __restrict__ r) {
  int m = blockIdx.x * 256 + threadIdx.x;
  if (m >= N_NODES) return;
  int i = m >> 5, j = m & 31;
  const float* arow = adj + (size_t)m * N_NODES;
  int n[5]; float c[5];
  n[0] = m;                      c[0] = arow[m];
  n[1] = (i > 0)  ? m - 32 : m;  c[1] = (i > 0)  ? arow[m - 32] : 0.f;
  n[2] = (i < 31) ? m + 32 : m;  c[2] = (i < 31) ? arow[m + 32] : 0.f;
  n[3] = (j > 0)  ? m - 1  : m;  c[3] = (j > 0)  ? arow[m - 1]  : 0.f;
  n[4] = (j < 31) ? m + 1  : m;  c[4] = (j < 31) ? arow[m + 1]  : 0.f;
  float s = 0.f;
#pragma unroll
  for (int t = 0; t < 5; t++) { nbi[m * 5 + t] = n[t]; nbc[m * 5 + t] = c[t]; s += c[t]; }
  r[m] = s;
}

// pack W1 [256,3] + b1 [256] -> [256][4] f32 (w0,w1,w2,b)
__global__ __launch_bounds__(256) void prep_w1_kernel(const float* __restrict__ W1,
                                                      const float* __restrict__ b1,
                                                      float* __restrict__ o) {
  int c = threadIdx.x;
  float4 v;
  v.x = W1[c * 3];
  v.y = W1[c * 3 + 1];
  v.z = W1[c * 3 + 2];
  v.w = b1[c];
  ((float4*)o)[c] = v;
}

__global__ __launch_bounds__(256) void outinit_kernel(const float* __restrict__ bc,
                                                      float* __restrict__ out) {
  int idx = blockIdx.x * 256 + threadIdx.x;
  if (idx < 256 * NCLS) out[idx] = bc[idx % NCLS];
}

// ---------------- fused layer1+agg+layer2: h2 = relu((A.h1) W2^T + r.b2) ----------------
// 512 threads / 8 waves per block; 128x256 output tile; 64x64 per-wave tile
// -> acc[4][4] = 64 AGPR, ~190 arch VGPRs free at the (512,2) cap: no spill
// (round-2's 256-thread version spilled: acc[4][8]=128 AGPR left only 128
// arch regs for the phase machinery -> +43 MB scratch traffic).
// Per K-chunk: Phase1 computes each halo h1 value ONCE into swizzled h1c;
// Phase2 aggregates the 5-point stencil h1c->As; Phase1(kq+1) overlaps the
// MFMA of kq via the co-resident wave on each SIMD.
__global__ __launch_bounds__(512, 2) void l12mm_kernel(
    const float* __restrict__ x,     // [chunk,3,1024]
    const float* __restrict__ w1p,   // [256][4] f32: w0,w1,w2,b1
    const u16* __restrict__ W2b,     // [256,256] bf16
    const float* __restrict__ b2,    // [256]
    const float* __restrict__ r,     // [1024]
    const int* __restrict__ nbi, const float* __restrict__ nbc,
    u16* __restrict__ C)             // h2 [M,256] bf16
{
  const int K = 256;
  __shared__ u16 As[128 * 64];       // 16 KB (swizzled)
  __shared__ u16 Bs[256 * 64];       // 32 KB (glds source-swizzled)
  __shared__ u16 h1c[192 * 64];      // 24 KB (swizzled)
  __shared__ float gxs[192][4];      // 3 KB  (gx0,gx1,gx2,rn) per halo node
  __shared__ float w1s[256][4];      // 4 KB

  int m0 = blockIdx.x * 128;
  int b = m0 >> 10;
  int node0 = m0 & 1023;
  int e0 = node0 - 32;
  int tid = threadIdx.x;
  int w = tid >> 6, l = tid & 63;
  int wm = w >> 2, wn = w & 3;

  // B staging (proven swizzled-glds layout; 8 waves x 32 rows each)
  int r8 = l >> 3, oct = l & 7;
  int so = (oct ^ r8) << 3;
  const u16* gb0 = W2b + (size_t)(w * 32 + r8) * K + so;

#define L12_ISSUEB(kq) \
  _Pragma("unroll") for (int q = 0; q < 4; q++) \
    async_copy16(gb0 + (size_t)q * 8 * K + (kq) * 64, &Bs[(w * 32 + q * 8) * 64]);

  L12_ISSUEB(0);

  // prologue: W1|b1 table + halo gx
  if (tid < 256) *(float4*)&w1s[tid][0] = ((const float4*)w1p)[tid];
  if (tid < 192) {
    int n = e0 + tid;
    float4 gv = {0.f, 0.f, 0.f, 0.f};
    if (n >= 0 && n < N_NODES) {
      const float* xb = x + (size_t)b * 3072;
      float g0 = 0.f, g1 = 0.f, g2 = 0.f;
#pragma unroll
      for (int t = 0; t < 5; t++) {
        int nb = nbi[n * 5 + t]; float cv = nbc[n * 5 + t];
        g0 += cv * xb[nb];
        g1 += cv * xb[1024 + nb];
        g2 += cv * xb[2048 + nb];
      }
      gv.x = g0; gv.y = g1; gv.z = g2; gv.w = r[n];
    }
    *(float4*)&gxs[tid][0] = gv;
  }

  // phase-1 assignment: thread -> (8-ch group cg, rows rb, rb+64, rb+128)
  int cg = tid & 7;
  int rb = tid >> 3;                 // 0..63
  int po1 = (cg ^ (rb & 7)) << 3;    // physical octet offset in h1c row

#define L12_PHASE1(kq_) { \
    float4 q_[8]; \
    _Pragma("unroll") for (int j = 0; j < 8; j++) \
      q_[j] = *(const float4*)&w1s[(kq_) * 64 + cg * 8 + j][0]; \
    _Pragma("unroll") for (int i = 0; i < 3; i++) { \
      int row_ = rb + 64 * i; \
      float4 g_ = *(const float4*)&gxs[row_][0]; \
      uint32_t pk_[4]; \
      _Pragma("unroll") for (int j = 0; j < 8; j += 2) { \
        float h0_ = fmaxf(fmaf(g_.x, q_[j].x, fmaf(g_.y, q_[j].y, fmaf(g_.z, q_[j].z, g_.w * q_[j].w))), 0.f); \
        float h1_ = fmaxf(fmaf(g_.x, q_[j+1].x, fmaf(g_.y, q_[j+1].y, fmaf(g_.z, q_[j+1].z, g_.w * q_[j+1].w))), 0.f); \
        pk_[j >> 1] = pkbf(h0_, h1_); \
      } \
      *(uint4*)&h1c[row_ * 64 + po1] = *(uint4*)pk_; \
    } }

  // phase-2 assignment: thread -> (octet oct2, rows ar2, ar2+64)
  int oct2 = tid & 7;
  int ar2 = tid >> 3;                // 0..63
  int pidx[2][5]; float pcf[2][5];
#pragma unroll
  for (int rr = 0; rr < 2; rr++) {
    int node = node0 + ar2 + 64 * rr;
#pragma unroll
    for (int t = 0; t < 5; t++) {
      pidx[rr][t] = nbi[node * 5 + t] - e0;   // always in [0,192)
      pcf[rr][t]  = nbc[node * 5 + t];
    }
  }
  int asw2 = (oct2 ^ (ar2 & 7)) << 3;  // As store swizzle (row&7 == ar2&7)

#define L12_PHASE2() \
  _Pragma("unroll") for (int rr = 0; rr < 2; rr++) { \
    float2 a2_[4] = {}; \
    _Pragma("unroll") for (int t = 0; t < 5; t++) { \
      int id_ = pidx[rr][t]; \
      uint4 v_ = *(const uint4*)&h1c[id_ * 64 + ((oct2 ^ (id_ & 7)) << 3)]; \
      agg8(v_, pcf[rr][t], a2_); \
    } \
    uint4 o_; \
    o_.x = pkbf(a2_[0].x, a2_[0].y); o_.y = pkbf(a2_[1].x, a2_[1].y); \
    o_.z = pkbf(a2_[2].x, a2_[2].y); o_.w = pkbf(a2_[3].x, a2_[3].y); \
    *(uint4*)&As[(ar2 + 64 * rr) * 64 + asw2] = o_; \
  }

  __syncthreads();      // gxs + w1s ready
  L12_PHASE1(0);

  f32x4 acc[4][4] = {};
  int lrow = l & 15, lq = l >> 4;
  int s2 = lrow & 7;

#pragma unroll
  for (int kq = 0; kq < 4; kq++) {
    __syncthreads();            // (A) h1c(kq) visible; MFMA(kq-1) done (As/Bs free)
    if (kq) L12_ISSUEB(kq);     // W2 chunk kq in flight under phase2
    L12_PHASE2();               // h1c(kq) -> As
    __syncthreads();            // (B) As ready; Bs(kq) drained
    if (kq < 3) L12_PHASE1(kq + 1);   // overlaps MFMA via co-resident wave

    const u16* pa = &As[(wm * 64 + lrow) * 64];
    const u16* pb = &Bs[(wn * 64 + lrow) * 64];
#pragma unroll
    for (int kh = 0; kh < 2; kh++) {
      int po = (((kh << 2) | lq) ^ s2) << 3;   // physical octet offset (A and B)
      bf16x8 af[4], bf[4];
#pragma unroll
      for (int t = 0; t < 4; t++) {
        af[t] = *(const bf16x8*)(pa + t * 16 * 64 + po);
        bf[t] = *(const bf16x8*)(pb + t * 16 * 64 + po);
      }
#pragma unroll
      for (int mt = 0; mt < 4; mt++)
#pragma unroll
        for (int nt = 0; nt < 4; nt++)
          acc[mt][nt] = __builtin_amdgcn_mfma_f32_16x16x32_bf16(af[mt], bf[nt], acc[mt][nt], 0, 0, 0);
    }
  }
#undef L12_ISSUEB
#undef L12_PHASE1
#undef L12_PHASE2

#pragma unroll
  for (int mt = 0; mt < 4; mt++)
#pragma unroll
    for (int nt = 0; nt < 4; nt++) {
      f32x4 v = acc[mt][nt];
      int col = wn * 64 + nt * 16 + lrow;
      float bs = b2[col];
#pragma unroll
      for (int i2 = 0; i2 < 4; i2++) {
        int row = m0 + wm * 64 + mt * 16 + lq * 4 + i2;
        float val = v[i2] + r[row & 1023] * bs;
        C[(size_t)row * 256 + col] = f2b(fmaxf(val, 0.f));
      }
    }
}

// ---------------- mm3agg: h3 = relu((A h2) W3^T + r.b3) ----------------
__global__ __launch_bounds__(256, 2) void mm3agg_kernel(
    const u16* __restrict__ H,      // h2 [chunk*1024, 256]
    const u16* __restrict__ W,      // W3b [128, 256]
    const float* __restrict__ bias, const float* __restrict__ r,
    const int* __restrict__ nbi, const float* __restrict__ nbc,
    u16* __restrict__ C)            // h3 [chunk*1024, 128]
{
  const int K = 256, N = 128;
  const int AST = 72;               // padded A row stride (elements)
  __shared__ u16 As[2][128 * AST];  // 2x18 KB
  __shared__ u16 Bs[2][128 * 64];   // 2x16 KB
  int m0 = blockIdx.x * 128;
  int tid = threadIdx.x;
  int w = tid >> 6, l = tid & 63;
  int wm = w >> 1, wn = w & 1;

  // aggregation: thread -> (row = tid/2, 32-col half of each 64-k chunk)
  int arow = tid >> 1;
  int acol = (tid & 1) * 32;
  int pg = m0 + arow;
  int node = pg & 1023;
  const u16* hb = H + ((size_t)(pg >> 10) << 10) * 256 + acol;
  const u16* nbp[5]; float cf[5];
#pragma unroll
  for (int j = 0; j < 5; j++) {
    nbp[j] = hb + (size_t)nbi[node * 5 + j] * 256;
    cf[j] = nbc[node * 5 + j];
  }

  // B staging
  int r8 = l >> 3, oct = l & 7;
  int so = (oct ^ r8) << 3;
  const u16* gb0 = W + (size_t)(w * 32 + r8) * K + so;

#define M3_ISSUEB(kq, buf) \
  _Pragma("unroll") for (int q = 0; q < 4; q++) \
    async_copy16(gb0 + (size_t)q * 8 * K + (kq) * 64, &Bs[buf][(w * 32 + q * 8) * 64]);

#define M3_LOADA(kq) \
  _Pragma("unroll") for (int j = 0; j < 5; j++) \
    _Pragma("unroll") for (int q = 0; q < 4; q++) \
      L[j][q] = *(const uint4*)(nbp[j] + (kq) * 64 + q * 8);

#define M3_AGGSTORE(buf) { \
  u16* dst = &As[buf][arow * AST + acol]; \
  _Pragma("unroll") for (int q = 0; q < 4; q++) { \
    float2 acc2[4] = {}; \
    _Pragma("unroll") for (int j = 0; j < 5; j++) agg8(L[j][q], cf[j], acc2); \
    uint4 o; \
    o.x = pkbf(acc2[0].x, acc2[0].y); o.y = pkbf(acc2[1].x, acc2[1].y); \
    o.z = pkbf(acc2[2].x, acc2[2].y); o.w = pkbf(acc2[3].x, acc2[3].y); \
    *(uint4*)(dst + q * 8) = o; \
  } }

  uint4 L[5][4];
  M3_ISSUEB(0, 0);
  M3_LOADA(0);
  M3_AGGSTORE(0);

  f32x4 acc[4][4] = {};
  int lrow = l & 15, lq = l >> 4;
  int s = lrow & 7;

#pragma unroll
  for (int kq = 0; kq < 4; kq++) {
    int buf = kq & 1;
    __syncthreads();
    if (kq < 3) {
      M3_ISSUEB(kq + 1, buf ^ 1);
      M3_LOADA(kq + 1);               // in flight during MFMA below
    }
    const u16* pa = &As[buf][(wm * 64 + lrow) * AST];
    const u16* pb = &Bs[buf][(wn * 64 + lrow) * 64];
#pragma unroll
    for (int kh = 0; kh < 2; kh++) {
      int po = (((kh << 2) | lq) ^ s) << 3;
      bf16x8 af[4], bf[4];
#pragma unroll
      for (int t = 0; t < 4; t++) {
        af[t] = *(const bf16x8*)(pa + t * 16 * AST + kh * 32 + lq * 8);
        bf[t] = *(const bf16x8*)(pb + t * 16 * 64 + po);
      }
#pragma unroll
      for (int mt = 0; mt < 4; mt++)
#pragma unroll
        for (int nt = 0; nt < 4; nt++)
          acc[mt][nt] = __builtin_amdgcn_mfma_f32_16x16x32_bf16(af[mt], bf[nt], acc[mt][nt], 0, 0, 0);
    }
    if (kq < 3) M3_AGGSTORE(buf ^ 1);
  }
#undef M3_ISSUEB
#undef M3_LOADA
#undef M3_AGGSTORE

#pragma unroll
  for (int mt = 0; mt < 4; mt++)
#pragma unroll
    for (int nt = 0; nt < 4; nt++) {
      f32x4 v = acc[mt][nt];
      int col = wn * 64 + nt * 16 + lrow;
      float bs = bias[col];
#pragma unroll
      for (int i2 = 0; i2 < 4; i2++) {
        int row = m0 + wm * 64 + mt * 16 + lq * 4 + i2;
        float val = v[i2] + r[row & 1023] * bs;
        C[(size_t)row * N + col] = f2b(fmaxf(val, 0.f));
      }
    }
}

// ---------------- classifier ----------------
__global__ __launch_bounds__(256) void cls_kernel(
    const u16* __restrict__ h3,   // [chunk, KDIM] bf16
    const u16* __restrict__ Wcb,  // [16, KDIM] bf16 (rows 10..15 zero)
    float* __restrict__ out,      // [256, 10]
    int b0)
{
  int mt = blockIdx.x;
  int split = blockIdx.y;
  int w = threadIdx.x >> 6, l = threadIdx.x & 63;
  int lrow = l & 15, lq = l >> 4;
  f32x4 acc = {};
  int kbase = split * 4096 + w * 1024;
  const u16* pa = h3 + (size_t)(mt * 16 + lrow) * KDIM + kbase + lq * 8;
  const u16* pb = Wcb + (size_t)lrow * KDIM + kbase + lq * 8;
#pragma unroll 4
  for (int kk = 0; kk < 1024; kk += 32) {
    bf16x8 a = *(const bf16x8*)(pa + kk);
    bf16x8 b = *(const bf16x8*)(pb + kk);
    acc = __builtin_amdgcn_mfma_f32_16x16x32_bf16(a, b, acc, 0, 0, 0);
  }
  if (lrow < NCLS) {
#pragma unroll
    for (int i2 = 0; i2 < 4; i2++) {
      int b = b0 + mt * 16 + lq * 4 + i2;
      atomicAdd(&out[b * NCLS + lrow], acc[i2]);
    }
  }
}

extern "C" void kernel_launch(void* const* d_in, const int* in_sizes, int n_in,
                              void* d_out, int out_size, void* d_ws, size_t ws_size,
                              hipStream_t stream) {
  const float* x   = (const float*)d_in[0];
  const float* W1  = (const float*)d_in[1];
  const float* b1  = (const float*)d_in[2];
  const float* W2  = (const float*)d_in[3];
  const float* b2  = (const float*)d_in[4];
  const float* W3  = (const float*)d_in[5];
  const float* b3  = (const float*)d_in[6];
  const float* Wc  = (const float*)d_in[7];
  const float* bc  = (const float*)d_in[8];
  const float* adj = (const float*)d_in[9];
  float* out = (float*)d_out;
  const int B = 256;

  uint8_t* ws = (uint8_t*)d_ws;
  u16* W2b = (u16*)ws;  ws += (size_t)256 * 256 * 2;
  u16* W3b = (u16*)ws;  ws += (size_t)128 * 256 * 2;
  u16* Wcb = (u16*)ws;  ws += (size_t)16 * KDIM * 2;
  float* rr  = (float*)ws; ws += 1024 * 4;
  int*   nbi = (int*)ws;   ws += 1024 * 5 * 4;
  float* nbc = (float*)ws; ws += 1024 * 5 * 4;
  float* w1p = (float*)ws; ws += 256 * 4 * 4;
  uintptr_t al = ((uintptr_t)ws + 255) & ~(uintptr_t)255;
  ws = (uint8_t*)al;
  size_t used = (size_t)(ws - (uint8_t*)d_ws);
  size_t avail = (ws_size > used) ? ws_size - used : 0;
  int chunk = 256;
  while (chunk > 32 && (size_t)chunk * 1024 * 256 * 2 * 2 > avail) chunk >>= 1;
  u16* bufA = (u16*)ws;
  u16* bufB = bufA + (size_t)chunk * 1024 * 256;

  cvt_w_kernel<<<256, 256, 0, stream>>>(W2, W2b, 256 * 256);
  cvt_w_kernel<<<128, 256, 0, stream>>>(W3, W3b, 128 * 256);
  prep_wc_kernel<<<(16 * KDIM) / 256, 256, 0, stream>>>(Wc, Wcb);
  prep_tab_kernel<<<4, 256, 0, stream>>>(adj, nbi, nbc, rr);
  prep_w1_kernel<<<1, 256, 0, stream>>>(W1, b1, w1p);
  outinit_kernel<<<(256 * NCLS + 255) / 256, 256, 0, stream>>>(bc, out);

  for (int b0 = 0; b0 < B; b0 += chunk) {
    const float* xb = x + (size_t)b0 * 3 * 1024;
    int M = chunk * 1024;
    // h2 = relu((A.h1) W2^T + r.b2) fused from x -> bufA
    l12mm_kernel<<<M / 128, 512, 0, stream>>>(xb, w1p, W2b, b2, rr, nbi, nbc, bufA);
    // h3 = relu((A.h2) W3^T + r.b3) -> bufB
    mm3agg_kernel<<<M / 128, 256, 0, stream>>>(bufA, W3b, b3, rr, nbi, nbc, bufB);
    dim3 gc(chunk / 16, 32);
    cls_kernel<<<gc, 256, 0, stream>>>(bufB, Wcb, out, b0);
  }
}

// Round 4
// 307.412 us; speedup vs baseline: 1.1171x; 1.0788x over previous
//
#include <hip/hip_runtime.h>
#include <stdint.h>

#define N_NODES 1024
#define NCLS 10
#define KDIM 131072  // 1024*128

typedef unsigned short u16;
typedef __bf16 bf16x8 __attribute__((ext_vector_type(8)));
typedef float f32x4 __attribute__((ext_vector_type(4)));

__device__ __forceinline__ float b2f_lo(uint32_t u) {
  union { float f; uint32_t u; } v; v.u = u << 16; return v.f;
}
__device__ __forceinline__ float b2f_hi(uint32_t u) {
  union { float f; uint32_t u; } v; v.u = u & 0xFFFF0000u; return v.f;
}
__device__ __forceinline__ u16 f2b(float f) {
  union { float f; uint32_t u; } v; v.f = f;
  uint32_t r = v.u + 0x7FFF + ((v.u >> 16) & 1);
  return (u16)(r >> 16);
}
__device__ __forceinline__ uint32_t pkbf(float a, float b) {
#if __has_builtin(__builtin_amdgcn_cvt_pk_bf16_f32)
  typedef __bf16 bf2 __attribute__((ext_vector_type(2)));
  bf2 r = __builtin_amdgcn_cvt_pk_bf16_f32(a, b);
  union { bf2 v; uint32_t u; } c; c.v = r; return c.u;
#else
  union { float f; uint32_t u; } va, vb; va.f = a; vb.f = b;
  uint32_t ra = (va.u + 0x7FFF + ((va.u >> 16) & 1)) >> 16;
  uint32_t rb = (vb.u + 0x7FFF + ((vb.u >> 16) & 1)) & 0xFFFF0000u;
  return ra | rb;
#endif
}

__device__ __forceinline__ void async_copy16(const u16* g, u16* l) {
  __builtin_amdgcn_global_load_lds(
      (const __attribute__((address_space(1))) void*)g,
      (__attribute__((address_space(3))) void*)l, 16, 0, 0);
}

// accumulate 8 bf16 (one uint4) scaled by c into float2 acc[4]
__device__ __forceinline__ void agg8(uint4 v, float c, float2* acc) {
  const uint32_t* u = (const uint32_t*)&v;
#pragma unroll
  for (int e = 0; e < 4; e++) {
    acc[e].x += c * b2f_lo(u[e]);
    acc[e].y += c * b2f_hi(u[e]);
  }
}

// ---------------- single merged prep kernel ----------------
// blockIdx ranges:
//   [0, 8192)        : WcT  (transposed classifier weights, [KDIM][16] bf16)
//   [8192, 8448)     : W2b  (256x256 f32->bf16)
//   [8448, 8576)     : W3b  (128x256 f32->bf16)
//   [8576, 8580)     : adj -> 5-point stencil tables (nbi, nbc, r)
//   [8580]           : w1p  (pack W1|b1 -> [256][4] f32)
//   [8581, 8591)     : out init (bc broadcast)
#define PREP_GRID 8591
__global__ __launch_bounds__(256) void prep_all_kernel(
    const float* __restrict__ W2, const float* __restrict__ W3,
    const float* __restrict__ Wc, const float* __restrict__ W1,
    const float* __restrict__ b1, const float* __restrict__ bc,
    const float* __restrict__ adj,
    u16* __restrict__ W2b, u16* __restrict__ W3b, u16* __restrict__ Wct,
    float* __restrict__ w1p, int* __restrict__ nbi, float* __restrict__ nbc,
    float* __restrict__ r, float* __restrict__ out)
{
  int blk = blockIdx.x;
  int tid = threadIdx.x;
  if (blk < 8192) {                       // WcT: i over KDIM*16, coalesced store
    int i = blk * 256 + tid;
    int col = i >> 4;                     // k position
    int row = i & 15;                     // class (10..15 -> zero)
    Wct[i] = (row < NCLS) ? f2b(Wc[(size_t)row * KDIM + col]) : (u16)0;
    return;
  }
  blk -= 8192;
  if (blk < 256) { int i = blk * 256 + tid; W2b[i] = f2b(W2[i]); return; }
  blk -= 256;
  if (blk < 128) { int i = blk * 256 + tid; W3b[i] = f2b(W3[i]); return; }
  blk -= 128;
  if (blk < 4) {
    int m = blk * 256 + tid;
    int i = m >> 5, j = m & 31;
    const float* arow = adj + (size_t)m * N_NODES;
    int n[5]; float c[5];
    n[0] = m;                      c[0] = arow[m];
    n[1] = (i > 0)  ? m - 32 : m;  c[1] = (i > 0)  ? arow[m - 32] : 0.f;
    n[2] = (i < 31) ? m + 32 : m;  c[2] = (i < 31) ? arow[m + 32] : 0.f;
    n[3] = (j > 0)  ? m - 1  : m;  c[3] = (j > 0)  ? arow[m - 1]  : 0.f;
    n[4] = (j < 31) ? m + 1  : m;  c[4] = (j < 31) ? arow[m + 1]  : 0.f;
    float s = 0.f;
#pragma unroll
    for (int t = 0; t < 5; t++) { nbi[m * 5 + t] = n[t]; nbc[m * 5 + t] = c[t]; s += c[t]; }
    r[m] = s;
    return;
  }
  blk -= 4;
  if (blk == 0) {
    float4 v;
    v.x = W1[tid * 3]; v.y = W1[tid * 3 + 1]; v.z = W1[tid * 3 + 2]; v.w = b1[tid];
    ((float4*)w1p)[tid] = v;
    return;
  }
  blk -= 1;
  int idx = blk * 256 + tid;
  if (idx < 256 * NCLS) out[idx] = bc[idx % NCLS];
}

// ---------------- fused layer1+agg+layer2: h2 = relu((A.h1) W2^T + r.b2) ----------------
// (proven round-1 structure: 256 thr, acc[4][8], AST=72 pad, VGPR 120, no spill)
// The A-tile (g2 = A.h1) is recomputed in-kernel from x (12 KB/image, L2-hot):
// gx = (A.x) for a 192-row halo is built once in the prologue; per 64-wide
// K-chunk each thread VALU-produces 32 g2 values straight into the padded
// A-LDS layout while the swizzled global_load_lds B-stage is in flight.
__global__ __launch_bounds__(256, 2) void l12mm_kernel(
    const float* __restrict__ x,     // [chunk,3,1024]
    const float* __restrict__ w1p,   // [256][4] f32: w0,w1,w2,b1
    const u16* __restrict__ W2b,     // [256,256] bf16
    const float* __restrict__ b2,    // [256]
    const float* __restrict__ r,     // [1024]
    const int* __restrict__ nbi, const float* __restrict__ nbc,
    u16* __restrict__ C)             // h2 [M,256] bf16
{
  const int K = 256;
  const int AST = 72;                // padded A row stride (elements)
  __shared__ u16 As[128 * AST];      // 18 KB
  __shared__ u16 Bs[256 * 64];       // 32 KB
  __shared__ float gxs[192][4];      // 3 KB  (gx0,gx1,gx2,rn) per halo node
  __shared__ float w1s[256][4];      // 4 KB

  int m0 = blockIdx.x * 128;
  int b = m0 >> 10;
  int node0 = m0 & 1023;
  int e0 = node0 - 32;
  int tid = threadIdx.x;
  int w = tid >> 6, l = tid & 63;
  int wm = w >> 1, wn = w & 1;

  // B staging (proven swizzled-glds layout)
  int r8 = l >> 3, oct = l & 7;
  int so = (oct ^ r8) << 3;
  const u16* gb0 = W2b + (size_t)(w * 64 + r8) * K + so;

#define L12_ISSUEB(kq) \
  _Pragma("unroll") for (int q = 0; q < 8; q++) \
    async_copy16(gb0 + (size_t)q * 8 * K + (kq) * 64, &Bs[(w * 64 + q * 8) * 64]);

  L12_ISSUEB(0);

  // prologue: W1|b1 table + halo gx
  *(float4*)&w1s[tid][0] = ((const float4*)w1p)[tid];
  if (tid < 192) {
    int n = e0 + tid;
    float4 gv = {0.f, 0.f, 0.f, 0.f};
    if (n >= 0 && n < N_NODES) {
      const float* xb = x + (size_t)b * 3072;
      float g0 = 0.f, g1 = 0.f, g2 = 0.f;
#pragma unroll
      for (int t = 0; t < 5; t++) {
        int nb = nbi[n * 5 + t]; float cv = nbc[n * 5 + t];
        g0 += cv * xb[nb];
        g1 += cv * xb[1024 + nb];
        g2 += cv * xb[2048 + nb];
      }
      gv.x = g0; gv.y = g1; gv.z = g2; gv.w = r[n];
    }
    *(float4*)&gxs[tid][0] = gv;
  }

  // per-thread A-production assignment: row = tid>>1, 32-channel half
  int arow = tid >> 1;
  int col0 = (tid & 1) * 32;
  int node = node0 + arow;
  int idx5[5]; float cf5[5];
#pragma unroll
  for (int t = 0; t < 5; t++) {
    idx5[t] = nbi[node * 5 + t] - e0;   // always in [0,192)
    cf5[t] = nbc[node * 5 + t];
  }

  __syncthreads();   // gxs + w1s ready (Bs(0) also drained here; prologue hid it)

  float4 gx[5];
#pragma unroll
  for (int t = 0; t < 5; t++) gx[t] = *(const float4*)&gxs[idx5[t]][0];

  f32x4 acc[4][8] = {};
  int lrow = l & 15, lq = l >> 4;
  int s2 = lrow & 7;

  for (int kq = 0; kq < 4; kq++) {
    if (kq) {
      __syncthreads();     // everyone done reading prev As/Bs
      L12_ISSUEB(kq);      // W2 chunk in flight under the VALU block below
    }
    // produce g2 tile chunk: 32 channels of row arow
    {
      u16* dst = &As[arow * AST + col0];
#pragma unroll
      for (int g = 0; g < 4; g++) {
        uint32_t pk[4];
#pragma unroll
        for (int jj = 0; jj < 8; jj += 2) {
          int c = kq * 64 + col0 + g * 8 + jj;
          float4 q0 = *(const float4*)&w1s[c][0];
          float4 q1 = *(const float4*)&w1s[c + 1][0];
          float a0 = 0.f, a1 = 0.f;
#pragma unroll
          for (int t = 0; t < 5; t++) {
            float h0 = fmaxf(gx[t].x * q0.x + gx[t].y * q0.y + gx[t].z * q0.z + gx[t].w * q0.w, 0.f);
            float h1 = fmaxf(gx[t].x * q1.x + gx[t].y * q1.y + gx[t].z * q1.z + gx[t].w * q1.w, 0.f);
            a0 += cf5[t] * h0;
            a1 += cf5[t] * h1;
          }
          pk[jj >> 1] = pkbf(a0, a1);
        }
        *(uint4*)(dst + g * 8) = *(uint4*)pk;
      }
    }
    __syncthreads();       // As visible + Bs glds drained

    const u16* pa = &As[(wm * 64 + lrow) * AST];
    const u16* pb = &Bs[(wn * 128 + lrow) * 64];
#pragma unroll
    for (int kh = 0; kh < 2; kh++) {
      int po = (((kh << 2) | lq) ^ s2) << 3;   // physical octet offset (B swizzle)
      bf16x8 af[4], bf[8];
#pragma unroll
      for (int t = 0; t < 4; t++)
        af[t] = *(const bf16x8*)(pa + t * 16 * AST + kh * 32 + lq * 8);
#pragma unroll
      for (int t = 0; t < 8; t++)
        bf[t] = *(const bf16x8*)(pb + t * 16 * 64 + po);
#pragma unroll
      for (int mt = 0; mt < 4; mt++)
#pragma unroll
        for (int nt = 0; nt < 8; nt++)
          acc[mt][nt] = __builtin_amdgcn_mfma_f32_16x16x32_bf16(af[mt], bf[nt], acc[mt][nt], 0, 0, 0);
    }
  }
#undef L12_ISSUEB

#pragma unroll
  for (int mt = 0; mt < 4; mt++)
#pragma unroll
    for (int nt = 0; nt < 8; nt++) {
      f32x4 v = acc[mt][nt];
      int col = wn * 128 + nt * 16 + lrow;
      float bs = b2[col];
#pragma unroll
      for (int i2 = 0; i2 < 4; i2++) {
        int row = m0 + wm * 64 + mt * 16 + lq * 4 + i2;
        float val = v[i2] + r[row & 1023] * bs;
        C[(size_t)row * 256 + col] = f2b(fmaxf(val, 0.f));
      }
    }
}

// ---------------- mm3agg + fused classifier ----------------
// h3 = relu((A h2) W3^T + r.b3) stays in registers; classifier contribution
// out[b] += vec(h3_tile) . WcT is accumulated in the epilogue (10 classes,
// WcT [KDIM][16] bf16 columns contiguous), wave shfl-reduced, one atomicAdd
// per class per block. h3 is never written to HBM; cls kernel deleted.
__global__ __launch_bounds__(256, 2) void mm3agg_kernel(
    const u16* __restrict__ H,      // h2 [chunk*1024, 256]
    const u16* __restrict__ W,      // W3b [128, 256]
    const float* __restrict__ bias, const float* __restrict__ r,
    const int* __restrict__ nbi, const float* __restrict__ nbc,
    const u16* __restrict__ Wct,    // [KDIM][16] bf16
    float* __restrict__ out,        // [256,10] f32 (pre-initialized to bc)
    int b0)
{
  const int K = 256;
  const int AST = 72;               // padded A row stride (elements)
  __shared__ u16 As[2][128 * AST];  // 2x18 KB
  __shared__ u16 Bs[2][128 * 64];   // 2x16 KB
  __shared__ float cred[4][NCLS];
  int m0 = blockIdx.x * 128;
  int tid = threadIdx.x;
  int w = tid >> 6, l = tid & 63;
  int wm = w >> 1, wn = w & 1;

  // aggregation: thread -> (row = tid/2, 32-col half of each 64-k chunk)
  int arow = tid >> 1;
  int acol = (tid & 1) * 32;
  int pg = m0 + arow;
  int node = pg & 1023;
  const u16* hb = H + ((size_t)(pg >> 10) << 10) * 256 + acol;
  const u16* nbp[5]; float cf[5];
#pragma unroll
  for (int j = 0; j < 5; j++) {
    nbp[j] = hb + (size_t)nbi[node * 5 + j] * 256;
    cf[j] = nbc[node * 5 + j];
  }

  // B staging
  int r8 = l >> 3, oct = l & 7;
  int so = (oct ^ r8) << 3;
  const u16* gb0 = W + (size_t)(w * 32 + r8) * K + so;

#define M3_ISSUEB(kq, buf) \
  _Pragma("unroll") for (int q = 0; q < 4; q++) \
    async_copy16(gb0 + (size_t)q * 8 * K + (kq) * 64, &Bs[buf][(w * 32 + q * 8) * 64]);

#define M3_LOADA(kq) \
  _Pragma("unroll") for (int j = 0; j < 5; j++) \
    _Pragma("unroll") for (int q = 0; q < 4; q++) \
      L[j][q] = *(const uint4*)(nbp[j] + (kq) * 64 + q * 8);

#define M3_AGGSTORE(buf) { \
  u16* dst = &As[buf][arow * AST + acol]; \
  _Pragma("unroll") for (int q = 0; q < 4; q++) { \
    float2 acc2[4] = {}; \
    _Pragma("unroll") for (int j = 0; j < 5; j++) agg8(L[j][q], cf[j], acc2); \
    uint4 o; \
    o.x = pkbf(acc2[0].x, acc2[0].y); o.y = pkbf(acc2[1].x, acc2[1].y); \
    o.z = pkbf(acc2[2].x, acc2[2].y); o.w = pkbf(acc2[3].x, acc2[3].y); \
    *(uint4*)(dst + q * 8) = o; \
  } }

  uint4 L[5][4];
  M3_ISSUEB(0, 0);
  M3_LOADA(0);
  M3_AGGSTORE(0);

  f32x4 acc[4][4] = {};
  int lrow = l & 15, lq = l >> 4;
  int s = lrow & 7;

#pragma unroll
  for (int kq = 0; kq < 4; kq++) {
    int buf = kq & 1;
    __syncthreads();
    if (kq < 3) {
      M3_ISSUEB(kq + 1, buf ^ 1);
      M3_LOADA(kq + 1);               // in flight during MFMA below
    }
    const u16* pa = &As[buf][(wm * 64 + lrow) * AST];
    const u16* pb = &Bs[buf][(wn * 64 + lrow) * 64];
#pragma unroll
    for (int kh = 0; kh < 2; kh++) {
      int po = (((kh << 2) | lq) ^ s) << 3;
      bf16x8 af[4], bf[4];
#pragma unroll
      for (int t = 0; t < 4; t++) {
        af[t] = *(const bf16x8*)(pa + t * 16 * AST + kh * 32 + lq * 8);
        bf[t] = *(const bf16x8*)(pb + t * 16 * 64 + po);
      }
#pragma unroll
      for (int mt = 0; mt < 4; mt++)
#pragma unroll
        for (int nt = 0; nt < 4; nt++)
          acc[mt][nt] = __builtin_amdgcn_mfma_f32_16x16x32_bf16(af[mt], bf[nt], acc[mt][nt], 0, 0, 0);
    }
    if (kq < 3) M3_AGGSTORE(buf ^ 1);
  }
#undef M3_ISSUEB
#undef M3_LOADA
#undef M3_AGGSTORE

  // ---- epilogue: h3 in regs -> classifier partials ----
  float p[NCLS];
#pragma unroll
  for (int c = 0; c < NCLS; c++) p[c] = 0.f;

#pragma unroll
  for (int mt = 0; mt < 4; mt++)
#pragma unroll
    for (int nt = 0; nt < 4; nt++) {
      f32x4 v = acc[mt][nt];
      int col = wn * 64 + nt * 16 + lrow;
      float bs = bias[col];
#pragma unroll
      for (int i2 = 0; i2 < 4; i2++) {
        int row = m0 + wm * 64 + mt * 16 + lq * 4 + i2;
        float h = fmaxf(v[i2] + r[row & 1023] * bs, 0.f);
        size_t wpos = (size_t)((row & 1023) * 128 + col) * 16;
        uint4 wv = *(const uint4*)&Wct[wpos];          // classes 0..7
        uint32_t wv8 = *(const uint32_t*)&Wct[wpos + 8];  // classes 8,9
        const uint32_t* wu = (const uint32_t*)&wv;
        p[0] += h * b2f_lo(wu[0]); p[1] += h * b2f_hi(wu[0]);
        p[2] += h * b2f_lo(wu[1]); p[3] += h * b2f_hi(wu[1]);
        p[4] += h * b2f_lo(wu[2]); p[5] += h * b2f_hi(wu[2]);
        p[6] += h * b2f_lo(wu[3]); p[7] += h * b2f_hi(wu[3]);
        p[8] += h * b2f_lo(wv8);   p[9] += h * b2f_hi(wv8);
      }
    }

  // wave reduce 10 partials
#pragma unroll
  for (int c = 0; c < NCLS; c++) {
#pragma unroll
    for (int off = 32; off; off >>= 1)
      p[c] += __shfl_xor(p[c], off, 64);
  }
  if (l == 0) {
#pragma unroll
    for (int c = 0; c < NCLS; c++) cred[w][c] = p[c];
  }
  __syncthreads();
  if (tid < NCLS) {
    int bimg = b0 + (m0 >> 10);
    float sum = cred[0][tid] + cred[1][tid] + cred[2][tid] + cred[3][tid];
    atomicAdd(&out[bimg * NCLS + tid], sum);
  }
}

extern "C" void kernel_launch(void* const* d_in, const int* in_sizes, int n_in,
                              void* d_out, int out_size, void* d_ws, size_t ws_size,
                              hipStream_t stream) {
  const float* x   = (const float*)d_in[0];
  const float* W1  = (const float*)d_in[1];
  const float* b1  = (const float*)d_in[2];
  const float* W2  = (const float*)d_in[3];
  const float* b2  = (const float*)d_in[4];
  const float* W3  = (const float*)d_in[5];
  const float* b3  = (const float*)d_in[6];
  const float* Wc  = (const float*)d_in[7];
  const float* bc  = (const float*)d_in[8];
  const float* adj = (const float*)d_in[9];
  float* out = (float*)d_out;
  const int B = 256;

  uint8_t* ws = (uint8_t*)d_ws;
  u16* W2b = (u16*)ws;  ws += (size_t)256 * 256 * 2;
  u16* W3b = (u16*)ws;  ws += (size_t)128 * 256 * 2;
  u16* Wct = (u16*)ws;  ws += (size_t)KDIM * 16 * 2;
  float* rr  = (float*)ws; ws += 1024 * 4;
  int*   nbi = (int*)ws;   ws += 1024 * 5 * 4;
  float* nbc = (float*)ws; ws += 1024 * 5 * 4;
  float* w1p = (float*)ws; ws += 256 * 4 * 4;
  uintptr_t al = ((uintptr_t)ws + 255) & ~(uintptr_t)255;
  ws = (uint8_t*)al;
  size_t used = (size_t)(ws - (uint8_t*)d_ws);
  size_t avail = (ws_size > used) ? ws_size - used : 0;
  int chunk = 256;
  while (chunk > 32 && (size_t)chunk * 1024 * 256 * 2 > avail) chunk >>= 1;
  u16* bufA = (u16*)ws;   // h2 only; h3 is never materialized

  prep_all_kernel<<<PREP_GRID, 256, 0, stream>>>(W2, W3, Wc, W1, b1, bc, adj,
                                                 W2b, W3b, Wct, w1p, nbi, nbc, rr, out);

  for (int b0 = 0; b0 < B; b0 += chunk) {
    const float* xb = x + (size_t)b0 * 3 * 1024;
    int M = chunk * 1024;
    // h2 = relu((A.h1) W2^T + r.b2) fused from x -> bufA
    l12mm_kernel<<<M / 128, 256, 0, stream>>>(xb, w1p, W2b, b2, rr, nbi, nbc, bufA);
    // h3 = relu((A.h2) W3^T + r.b3) in-reg, classifier fused
    mm3agg_kernel<<<M / 128, 256, 0, stream>>>(bufA, W3b, b3, rr, nbi, nbc, Wct, out, b0);
  }
}

// Round 6
// 275.793 us; speedup vs baseline: 1.2451x; 1.1146x over previous
//
#include <hip/hip_runtime.h>
#include <stdint.h>

#define N_NODES 1024
#define NCLS 10
#define KDIM 131072  // 1024*128

typedef unsigned short u16;
typedef __bf16 bf16x8 __attribute__((ext_vector_type(8)));
typedef float f32x4 __attribute__((ext_vector_type(4)));

__device__ __forceinline__ float b2f_lo(uint32_t u) {
  union { float f; uint32_t u; } v; v.u = u << 16; return v.f;
}
__device__ __forceinline__ float b2f_hi(uint32_t u) {
  union { float f; uint32_t u; } v; v.u = u & 0xFFFF0000u; return v.f;
}
__device__ __forceinline__ u16 f2b(float f) {
  union { float f; uint32_t u; } v; v.f = f;
  uint32_t r = v.u + 0x7FFF + ((v.u >> 16) & 1);
  return (u16)(r >> 16);
}
__device__ __forceinline__ uint32_t pkbf(float a, float b) {
#if __has_builtin(__builtin_amdgcn_cvt_pk_bf16_f32)
  typedef __bf16 bf2 __attribute__((ext_vector_type(2)));
  bf2 r = __builtin_amdgcn_cvt_pk_bf16_f32(a, b);
  union { bf2 v; uint32_t u; } c; c.v = r; return c.u;
#else
  union { float f; uint32_t u; } va, vb; va.f = a; vb.f = b;
  uint32_t ra = (va.u + 0x7FFF + ((va.u >> 16) & 1)) >> 16;
  uint32_t rb = (vb.u + 0x7FFF + ((vb.u >> 16) & 1)) & 0xFFFF0000u;
  return ra | rb;
#endif
}

__device__ __forceinline__ void async_copy16(const u16* g, u16* l) {
  __builtin_amdgcn_global_load_lds(
      (const __attribute__((address_space(1))) void*)g,
      (__attribute__((address_space(3))) void*)l, 16, 0, 0);
}

// accumulate 8 bf16 (one uint4) scaled by c into float2 acc[4]
__device__ __forceinline__ void agg8(uint4 v, float c, float2* acc) {
  const uint32_t* u = (const uint32_t*)&v;
#pragma unroll
  for (int e = 0; e < 4; e++) {
    acc[e].x += c * b2f_lo(u[e]);
    acc[e].y += c * b2f_hi(u[e]);
  }
}

// ---------------- single merged prep kernel ----------------
// blockIdx ranges:
//   [0, 8192)        : Wcf  (classifier weights in MFMA B-fragment layout:
//                      flat idx = (kb*64 + lane)*8 + i, value =
//                      Wc[cls = lane&15][kb*32 + (lane>>4)*8 + i], cls>=10 -> 0)
//   [8192, 8448)     : W2b  (256x256 f32->bf16)
//   [8448, 8576)     : W3b  (128x256 f32->bf16)
//   [8576, 8580)     : adj -> 5-point stencil tables (nbi, nbc, r)
//   [8580]           : w1p  (pack W1|b1 -> [256][4] f32)
//   [8581, 8591)     : out init (bc broadcast)
#define PREP_GRID 8591
__global__ __launch_bounds__(256) void prep_all_kernel(
    const float* __restrict__ W2, const float* __restrict__ W3,
    const float* __restrict__ Wc, const float* __restrict__ W1,
    const float* __restrict__ b1, const float* __restrict__ bc,
    const float* __restrict__ adj,
    u16* __restrict__ W2b, u16* __restrict__ W3b, u16* __restrict__ Wcf,
    float* __restrict__ w1p, int* __restrict__ nbi, float* __restrict__ nbc,
    float* __restrict__ r, float* __restrict__ out)
{
  int blk = blockIdx.x;
  int tid = threadIdx.x;
  if (blk < 8192) {                       // Wcf: i over KDIM*16, coalesced store
    int i = blk * 256 + tid;
    int kb  = i >> 9;
    int l   = (i >> 3) & 63;
    int i8  = i & 7;
    int cls = l & 15;
    int kpos = kb * 32 + ((l >> 4) << 3) + i8;
    Wcf[i] = (cls < NCLS) ? f2b(Wc[(size_t)cls * KDIM + kpos]) : (u16)0;
    return;
  }
  blk -= 8192;
  if (blk < 256) { int i = blk * 256 + tid; W2b[i] = f2b(W2[i]); return; }
  blk -= 256;
  if (blk < 128) { int i = blk * 256 + tid; W3b[i] = f2b(W3[i]); return; }
  blk -= 128;
  if (blk < 4) {
    int m = blk * 256 + tid;
    int i = m >> 5, j = m & 31;
    const float* arow = adj + (size_t)m * N_NODES;
    int n[5]; float c[5];
    n[0] = m;                      c[0] = arow[m];
    n[1] = (i > 0)  ? m - 32 : m;  c[1] = (i > 0)  ? arow[m - 32] : 0.f;
    n[2] = (i < 31) ? m + 32 : m;  c[2] = (i < 31) ? arow[m + 32] : 0.f;
    n[3] = (j > 0)  ? m - 1  : m;  c[3] = (j > 0)  ? arow[m - 1]  : 0.f;
    n[4] = (j < 31) ? m + 1  : m;  c[4] = (j < 31) ? arow[m + 1]  : 0.f;
    float s = 0.f;
#pragma unroll
    for (int t = 0; t < 5; t++) { nbi[m * 5 + t] = n[t]; nbc[m * 5 + t] = c[t]; s += c[t]; }
    r[m] = s;
    return;
  }
  blk -= 4;
  if (blk == 0) {
    float4 v;
    v.x = W1[tid * 3]; v.y = W1[tid * 3 + 1]; v.z = W1[tid * 3 + 2]; v.w = b1[tid];
    ((float4*)w1p)[tid] = v;
    return;
  }
  blk -= 1;
  int idx = blk * 256 + tid;
  if (idx < 256 * NCLS) out[idx] = bc[idx % NCLS];
}

// ---------------- fused layer1+agg+layer2: h2 = relu((A.h1) W2^T + r.b2) ----------------
// (proven round-1 structure: 256 thr, acc[4][8], AST=72 pad, VGPR 120, no spill)
__global__ __launch_bounds__(256, 2) void l12mm_kernel(
    const float* __restrict__ x,     // [chunk,3,1024]
    const float* __restrict__ w1p,   // [256][4] f32: w0,w1,w2,b1
    const u16* __restrict__ W2b,     // [256,256] bf16
    const float* __restrict__ b2,    // [256]
    const float* __restrict__ r,     // [1024]
    const int* __restrict__ nbi, const float* __restrict__ nbc,
    u16* __restrict__ C)             // h2 [M,256] bf16
{
  const int K = 256;
  const int AST = 72;                // padded A row stride (elements)
  __shared__ u16 As[128 * AST];      // 18 KB
  __shared__ u16 Bs[256 * 64];       // 32 KB
  __shared__ float gxs[192][4];      // 3 KB  (gx0,gx1,gx2,rn) per halo node
  __shared__ float w1s[256][4];      // 4 KB

  int m0 = blockIdx.x * 128;
  int b = m0 >> 10;
  int node0 = m0 & 1023;
  int e0 = node0 - 32;
  int tid = threadIdx.x;
  int w = tid >> 6, l = tid & 63;
  int wm = w >> 1, wn = w & 1;

  // B staging (proven swizzled-glds layout)
  int r8 = l >> 3, oct = l & 7;
  int so = (oct ^ r8) << 3;
  const u16* gb0 = W2b + (size_t)(w * 64 + r8) * K + so;

#define L12_ISSUEB(kq) \
  _Pragma("unroll") for (int q = 0; q < 8; q++) \
    async_copy16(gb0 + (size_t)q * 8 * K + (kq) * 64, &Bs[(w * 64 + q * 8) * 64]);

  L12_ISSUEB(0);

  // prologue: W1|b1 table + halo gx
  *(float4*)&w1s[tid][0] = ((const float4*)w1p)[tid];
  if (tid < 192) {
    int n = e0 + tid;
    float4 gv = {0.f, 0.f, 0.f, 0.f};
    if (n >= 0 && n < N_NODES) {
      const float* xb = x + (size_t)b * 3072;
      float g0 = 0.f, g1 = 0.f, g2 = 0.f;
#pragma unroll
      for (int t = 0; t < 5; t++) {
        int nb = nbi[n * 5 + t]; float cv = nbc[n * 5 + t];
        g0 += cv * xb[nb];
        g1 += cv * xb[1024 + nb];
        g2 += cv * xb[2048 + nb];
      }
      gv.x = g0; gv.y = g1; gv.z = g2; gv.w = r[n];
    }
    *(float4*)&gxs[tid][0] = gv;
  }

  // per-thread A-production assignment: row = tid>>1, 32-channel half
  int arow = tid >> 1;
  int col0 = (tid & 1) * 32;
  int node = node0 + arow;
  int idx5[5]; float cf5[5];
#pragma unroll
  for (int t = 0; t < 5; t++) {
    idx5[t] = nbi[node * 5 + t] - e0;   // always in [0,192)
    cf5[t] = nbc[node * 5 + t];
  }

  __syncthreads();   // gxs + w1s ready (Bs(0) also drained here; prologue hid it)

  float4 gx[5];
#pragma unroll
  for (int t = 0; t < 5; t++) gx[t] = *(const float4*)&gxs[idx5[t]][0];

  f32x4 acc[4][8] = {};
  int lrow = l & 15, lq = l >> 4;
  int s2 = lrow & 7;

  for (int kq = 0; kq < 4; kq++) {
    if (kq) {
      __syncthreads();     // everyone done reading prev As/Bs
      L12_ISSUEB(kq);      // W2 chunk in flight under the VALU block below
    }
    // produce g2 tile chunk: 32 channels of row arow
    {
      u16* dst = &As[arow * AST + col0];
#pragma unroll
      for (int g = 0; g < 4; g++) {
        uint32_t pk[4];
#pragma unroll
        for (int jj = 0; jj < 8; jj += 2) {
          int c = kq * 64 + col0 + g * 8 + jj;
          float4 q0 = *(const float4*)&w1s[c][0];
          float4 q1 = *(const float4*)&w1s[c + 1][0];
          float a0 = 0.f, a1 = 0.f;
#pragma unroll
          for (int t = 0; t < 5; t++) {
            float h0 = fmaxf(gx[t].x * q0.x + gx[t].y * q0.y + gx[t].z * q0.z + gx[t].w * q0.w, 0.f);
            float h1 = fmaxf(gx[t].x * q1.x + gx[t].y * q1.y + gx[t].z * q1.z + gx[t].w * q1.w, 0.f);
            a0 += cf5[t] * h0;
            a1 += cf5[t] * h1;
          }
          pk[jj >> 1] = pkbf(a0, a1);
        }
        *(uint4*)(dst + g * 8) = *(uint4*)pk;
      }
    }
    __syncthreads();       // As visible + Bs glds drained

    const u16* pa = &As[(wm * 64 + lrow) * AST];
    const u16* pb = &Bs[(wn * 128 + lrow) * 64];
#pragma unroll
    for (int kh = 0; kh < 2; kh++) {
      int po = (((kh << 2) | lq) ^ s2) << 3;   // physical octet offset (B swizzle)
      bf16x8 af[4], bf[8];
#pragma unroll
      for (int t = 0; t < 4; t++)
        af[t] = *(const bf16x8*)(pa + t * 16 * AST + kh * 32 + lq * 8);
#pragma unroll
      for (int t = 0; t < 8; t++)
        bf[t] = *(const bf16x8*)(pb + t * 16 * 64 + po);
#pragma unroll
      for (int mt = 0; mt < 4; mt++)
#pragma unroll
        for (int nt = 0; nt < 8; nt++)
          acc[mt][nt] = __builtin_amdgcn_mfma_f32_16x16x32_bf16(af[mt], bf[nt], acc[mt][nt], 0, 0, 0);
    }
  }
#undef L12_ISSUEB

#pragma unroll
  for (int mt = 0; mt < 4; mt++)
#pragma unroll
    for (int nt = 0; nt < 8; nt++) {
      f32x4 v = acc[mt][nt];
      int col = wn * 128 + nt * 16 + lrow;
      float bs = b2[col];
#pragma unroll
      for (int i2 = 0; i2 < 4; i2++) {
        int row = m0 + wm * 64 + mt * 16 + lq * 4 + i2;
        float val = v[i2] + r[row & 1023] * bs;
        C[(size_t)row * 256 + col] = f2b(fmaxf(val, 0.f));
      }
    }
}

// ---------------- mm3agg + MFMA classifier ----------------
// h3 = relu((A h2) W3^T + r.b3) -> LDS tile (never HBM); classifier done as
// 512 MFMAs/block: A = h3 flat-k broadcast (16 identical rows — MFMA pipe is
// idle anyway), B = Wcf fragment (lane&15 = class, contiguous 16 B per lane
// per step). Each lane's D value is the complete k-sum for its class; one
// LDS write per wave + one atomicAdd per block.
__global__ __launch_bounds__(256, 2) void mm3agg_kernel(
    const u16* __restrict__ H,      // h2 [chunk*1024, 256]
    const u16* __restrict__ W,      // W3b [128, 256]
    const float* __restrict__ bias, const float* __restrict__ r,
    const int* __restrict__ nbi, const float* __restrict__ nbc,
    const u16* __restrict__ Wcf,    // [KDIM/32][64][8] bf16 B-frag layout
    float* __restrict__ out,        // [256,10] f32 (pre-initialized to bc)
    int b0)
{
  const int K = 256;
  const int AST = 72;               // padded A row stride (elements)
  __shared__ u16 As[2][128 * AST];  // 2x18 KB (reused as 32 KB h3 tile after K-loop)
  __shared__ u16 Bs[2][128 * 64];   // 2x16 KB
  __shared__ float cred[4][NCLS];
  int m0 = blockIdx.x * 128;
  int tid = threadIdx.x;
  int w = tid >> 6, l = tid & 63;
  int wm = w >> 1, wn = w & 1;

  // aggregation: thread -> (row = tid/2, 32-col half of each 64-k chunk)
  int arow = tid >> 1;
  int acol = (tid & 1) * 32;
  int pg = m0 + arow;
  int node = pg & 1023;
  const u16* hb = H + ((size_t)(pg >> 10) << 10) * 256 + acol;
  const u16* nbp[5]; float cf[5];
#pragma unroll
  for (int j = 0; j < 5; j++) {
    nbp[j] = hb + (size_t)nbi[node * 5 + j] * 256;
    cf[j] = nbc[node * 5 + j];
  }

  // B staging
  int r8 = l >> 3, oct = l & 7;
  int so = (oct ^ r8) << 3;
  const u16* gb0 = W + (size_t)(w * 32 + r8) * K + so;

#define M3_ISSUEB(kq, buf) \
  _Pragma("unroll") for (int q = 0; q < 4; q++) \
    async_copy16(gb0 + (size_t)q * 8 * K + (kq) * 64, &Bs[buf][(w * 32 + q * 8) * 64]);

#define M3_LOADA(kq) \
  _Pragma("unroll") for (int j = 0; j < 5; j++) \
    _Pragma("unroll") for (int q = 0; q < 4; q++) \
      L[j][q] = *(const uint4*)(nbp[j] + (kq) * 64 + q * 8);

#define M3_AGGSTORE(buf) { \
  u16* dst = &As[buf][arow * AST + acol]; \
  _Pragma("unroll") for (int q = 0; q < 4; q++) { \
    float2 acc2[4] = {}; \
    _Pragma("unroll") for (int j = 0; j < 5; j++) agg8(L[j][q], cf[j], acc2); \
    uint4 o; \
    o.x = pkbf(acc2[0].x, acc2[0].y); o.y = pkbf(acc2[1].x, acc2[1].y); \
    o.z = pkbf(acc2[2].x, acc2[2].y); o.w = pkbf(acc2[3].x, acc2[3].y); \
    *(uint4*)(dst + q * 8) = o; \
  } }

  uint4 L[5][4];
  M3_ISSUEB(0, 0);
  M3_LOADA(0);
  M3_AGGSTORE(0);

  f32x4 acc[4][4] = {};
  int lrow = l & 15, lq = l >> 4;
  int s = lrow & 7;

#pragma unroll
  for (int kq = 0; kq < 4; kq++) {
    int buf = kq & 1;
    __syncthreads();
    if (kq < 3) {
      M3_ISSUEB(kq + 1, buf ^ 1);
      M3_LOADA(kq + 1);               // in flight during MFMA below
    }
    const u16* pa = &As[buf][(wm * 64 + lrow) * AST];
    const u16* pb = &Bs[buf][(wn * 64 + lrow) * 64];
#pragma unroll
    for (int kh = 0; kh < 2; kh++) {
      int po = (((kh << 2) | lq) ^ s) << 3;
      bf16x8 af[4], bf[4];
#pragma unroll
      for (int t = 0; t < 4; t++) {
        af[t] = *(const bf16x8*)(pa + t * 16 * AST + kh * 32 + lq * 8);
        bf[t] = *(const bf16x8*)(pb + t * 16 * 64 + po);
      }
#pragma unroll
      for (int mt = 0; mt < 4; mt++)
#pragma unroll
        for (int nt = 0; nt < 4; nt++)
          acc[mt][nt] = __builtin_amdgcn_mfma_f32_16x16x32_bf16(af[mt], bf[nt], acc[mt][nt], 0, 0, 0);
    }
    if (kq < 3) M3_AGGSTORE(buf ^ 1);
  }
#undef M3_ISSUEB
#undef M3_LOADA
#undef M3_AGGSTORE

  // ---- epilogue: h3 -> LDS tile, classifier via MFMA ----
  __syncthreads();                 // K-loop reads of As/Bs done
  u16* h3s = (u16*)As;             // [128][128] bf16 = 32 KB
#pragma unroll
  for (int mt = 0; mt < 4; mt++)
#pragma unroll
    for (int nt = 0; nt < 4; nt++) {
      f32x4 v = acc[mt][nt];
      int col = wn * 64 + nt * 16 + lrow;
      float bs = bias[col];
#pragma unroll
      for (int i2 = 0; i2 < 4; i2++) {
        int lr = wm * 64 + mt * 16 + lq * 4 + i2;
        float h = fmaxf(v[i2] + r[(m0 + lr) & 1023] * bs, 0.f);
        h3s[lr * 128 + col] = f2b(h);
      }
    }
  __syncthreads();                 // h3 tile visible

  // wave w covers local kb in [w*128, w*128+128); global kb = node0*4 + kb
  int node0 = m0 & 1023;
  const u16* wp = Wcf + ((size_t)(node0 * 4 + w * 128) * 64 + l) * 8;
  const u16* ap = h3s + w * 128 * 32 + lq * 8;
  f32x4 cacc = {};
#pragma unroll 8
  for (int t = 0; t < 128; t++) {
    bf16x8 bfv = *(const bf16x8*)(wp + (size_t)t * 512);  // 16 B coalesced, L2
    bf16x8 afv = *(const bf16x8*)(ap + t * 32);           // LDS broadcast
    cacc = __builtin_amdgcn_mfma_f32_16x16x32_bf16(afv, bfv, cacc, 0, 0, 0);
  }
  if (l < NCLS) cred[w][l] = cacc[0];   // col = l = class; full k-sum per lane
  __syncthreads();
  if (tid < NCLS) {
    int bimg = b0 + (m0 >> 10);
    atomicAdd(&out[bimg * NCLS + tid],
              cred[0][tid] + cred[1][tid] + cred[2][tid] + cred[3][tid]);
  }
}

extern "C" void kernel_launch(void* const* d_in, const int* in_sizes, int n_in,
                              void* d_out, int out_size, void* d_ws, size_t ws_size,
                              hipStream_t stream) {
  const float* x   = (const float*)d_in[0];
  const float* W1  = (const float*)d_in[1];
  const float* b1  = (const float*)d_in[2];
  const float* W2  = (const float*)d_in[3];
  const float* b2  = (const float*)d_in[4];
  const float* W3  = (const float*)d_in[5];
  const float* b3  = (const float*)d_in[6];
  const float* Wc  = (const float*)d_in[7];
  const float* bc  = (const float*)d_in[8];
  const float* adj = (const float*)d_in[9];
  float* out = (float*)d_out;
  const int B = 256;

  uint8_t* ws = (uint8_t*)d_ws;
  u16* W2b = (u16*)ws;  ws += (size_t)256 * 256 * 2;
  u16* W3b = (u16*)ws;  ws += (size_t)128 * 256 * 2;
  u16* Wcf = (u16*)ws;  ws += (size_t)KDIM * 16 * 2;
  float* rr  = (float*)ws; ws += 1024 * 4;
  int*   nbi = (int*)ws;   ws += 1024 * 5 * 4;
  float* nbc = (float*)ws; ws += 1024 * 5 * 4;
  float* w1p = (float*)ws; ws += 256 * 4 * 4;
  uintptr_t al = ((uintptr_t)ws + 255) & ~(uintptr_t)255;
  ws = (uint8_t*)al;
  size_t used = (size_t)(ws - (uint8_t*)d_ws);
  size_t avail = (ws_size > used) ? ws_size - used : 0;
  int chunk = 256;
  while (chunk > 32 && (size_t)chunk * 1024 * 256 * 2 > avail) chunk >>= 1;
  u16* bufA = (u16*)ws;   // h2 only; h3 is never materialized

  prep_all_kernel<<<PREP_GRID, 256, 0, stream>>>(W2, W3, Wc, W1, b1, bc, adj,
                                                 W2b, W3b, Wcf, w1p, nbi, nbc, rr, out);

  for (int b0 = 0; b0 < B; b0 += chunk) {
    const float* xb = x + (size_t)b0 * 3 * 1024;
    int M = chunk * 1024;
    // h2 = relu((A.h1) W2^T + r.b2) fused from x -> bufA
    l12mm_kernel<<<M / 128, 256, 0, stream>>>(xb, w1p, W2b, b2, rr, nbi, nbc, bufA);
    // h3 = relu((A.h2) W3^T + r.b3) in-reg/LDS, classifier via MFMA
    mm3agg_kernel<<<M / 128, 256, 0, stream>>>(bufA, W3b, b3, rr, nbi, nbc, Wcf, out, b0);
  }
}

// Round 7
// 271.688 us; speedup vs baseline: 1.2639x; 1.0151x over previous
//
#include <hip/hip_runtime.h>
#include <stdint.h>

#define N_NODES 1024
#define NCLS 10
#define KDIM 131072  // 1024*128

typedef unsigned short u16;
typedef __bf16 bf16x8 __attribute__((ext_vector_type(8)));
typedef float f32x4 __attribute__((ext_vector_type(4)));

__device__ __forceinline__ float b2f_lo(uint32_t u) {
  union { float f; uint32_t u; } v; v.u = u << 16; return v.f;
}
__device__ __forceinline__ float b2f_hi(uint32_t u) {
  union { float f; uint32_t u; } v; v.u = u & 0xFFFF0000u; return v.f;
}
__device__ __forceinline__ u16 f2b(float f) {
  union { float f; uint32_t u; } v; v.f = f;
  uint32_t r = v.u + 0x7FFF + ((v.u >> 16) & 1);
  return (u16)(r >> 16);
}
__device__ __forceinline__ uint32_t pkbf(float a, float b) {
#if __has_builtin(__builtin_amdgcn_cvt_pk_bf16_f32)
  typedef __bf16 bf2 __attribute__((ext_vector_type(2)));
  bf2 r = __builtin_amdgcn_cvt_pk_bf16_f32(a, b);
  union { bf2 v; uint32_t u; } c; c.v = r; return c.u;
#else
  union { float f; uint32_t u; } va, vb; va.f = a; vb.f = b;
  uint32_t ra = (va.u + 0x7FFF + ((va.u >> 16) & 1)) >> 16;
  uint32_t rb = (vb.u + 0x7FFF + ((vb.u >> 16) & 1)) & 0xFFFF0000u;
  return ra | rb;
#endif
}

__device__ __forceinline__ void async_copy16(const u16* g, u16* l) {
  __builtin_amdgcn_global_load_lds(
      (const __attribute__((address_space(1))) void*)g,
      (__attribute__((address_space(3))) void*)l, 16, 0, 0);
}

// accumulate 8 bf16 (one uint4) scaled by c into float2 acc[4]
__device__ __forceinline__ void agg8(uint4 v, float c, float2* acc) {
  const uint32_t* u = (const uint32_t*)&v;
#pragma unroll
  for (int e = 0; e < 4; e++) {
    acc[e].x += c * b2f_lo(u[e]);
    acc[e].y += c * b2f_hi(u[e]);
  }
}

// ---------------- single merged prep kernel ----------------
// blockIdx ranges:
//   [0, 8192)        : Wcf  (classifier weights in MFMA B-fragment layout:
//                      flat idx = (kb*64 + lane)*8 + i, value =
//                      Wc[cls = lane&15][kb*32 + (lane>>4)*8 + i], cls>=10 -> 0)
//   [8192, 8448)     : W2b  (256x256 f32->bf16)
//   [8448, 8576)     : W3b  (128x256 f32->bf16)
//   [8576, 8580)     : adj -> 5-point stencil tables (nbi, nbc, r)
//   [8580]           : w1p  (pack W1|b1 -> [256][4] f32)
//   [8581, 8591)     : out init (bc broadcast)
#define PREP_GRID 8591
__global__ __launch_bounds__(256) void prep_all_kernel(
    const float* __restrict__ W2, const float* __restrict__ W3,
    const float* __restrict__ Wc, const float* __restrict__ W1,
    const float* __restrict__ b1, const float* __restrict__ bc,
    const float* __restrict__ adj,
    u16* __restrict__ W2b, u16* __restrict__ W3b, u16* __restrict__ Wcf,
    float* __restrict__ w1p, int* __restrict__ nbi, float* __restrict__ nbc,
    float* __restrict__ r, float* __restrict__ out)
{
  int blk = blockIdx.x;
  int tid = threadIdx.x;
  if (blk < 8192) {                       // Wcf: i over KDIM*16, coalesced store
    int i = blk * 256 + tid;
    int kb  = i >> 9;
    int l   = (i >> 3) & 63;
    int i8  = i & 7;
    int cls = l & 15;
    int kpos = kb * 32 + ((l >> 4) << 3) + i8;
    Wcf[i] = (cls < NCLS) ? f2b(Wc[(size_t)cls * KDIM + kpos]) : (u16)0;
    return;
  }
  blk -= 8192;
  if (blk < 256) { int i = blk * 256 + tid; W2b[i] = f2b(W2[i]); return; }
  blk -= 256;
  if (blk < 128) { int i = blk * 256 + tid; W3b[i] = f2b(W3[i]); return; }
  blk -= 128;
  if (blk < 4) {
    int m = blk * 256 + tid;
    int i = m >> 5, j = m & 31;
    const float* arow = adj + (size_t)m * N_NODES;
    int n[5]; float c[5];
    n[0] = m;                      c[0] = arow[m];
    n[1] = (i > 0)  ? m - 32 : m;  c[1] = (i > 0)  ? arow[m - 32] : 0.f;
    n[2] = (i < 31) ? m + 32 : m;  c[2] = (i < 31) ? arow[m + 32] : 0.f;
    n[3] = (j > 0)  ? m - 1  : m;  c[3] = (j > 0)  ? arow[m - 1]  : 0.f;
    n[4] = (j < 31) ? m + 1  : m;  c[4] = (j < 31) ? arow[m + 1]  : 0.f;
    float s = 0.f;
#pragma unroll
    for (int t = 0; t < 5; t++) { nbi[m * 5 + t] = n[t]; nbc[m * 5 + t] = c[t]; s += c[t]; }
    r[m] = s;
    return;
  }
  blk -= 4;
  if (blk == 0) {
    float4 v;
    v.x = W1[tid * 3]; v.y = W1[tid * 3 + 1]; v.z = W1[tid * 3 + 2]; v.w = b1[tid];
    ((float4*)w1p)[tid] = v;
    return;
  }
  blk -= 1;
  int idx = blk * 256 + tid;
  if (idx < 256 * NCLS) out[idx] = bc[idx % NCLS];
}

// ---------------- fused layer1+agg+layer2: h2 = relu((A.h1) W2^T + r.b2) ----------------
// Dedup'd A-production on the proven 256-thr/acc[4][8]/2-blocks-per-CU skeleton:
//   phase1: each halo h1 value computed ONCE per kq into swizzled h1c[192][64]
//           (w1 coeffs loaded just-in-time from global in 16-reg batches - no
//           64-reg hoist, no spill; R2's failure mode avoided)
//   phase2: 5-point stencil aggregation h1c -> As (XOR-octet swizzle, same po
//           read path as Bs; formulas correctness-proven in R3)
//   phase1(kq+1) co-scheduled with MFMA(kq) (independent pipes); phase2
//   overlaps the Bs glds flight. LDS 75 KB -> 2 blocks/CU (R3 failed as a
//   register-limited single-block convoy; 256-thr keeps 2 barrier domains).
__global__ __launch_bounds__(256, 2) void l12mm_kernel(
    const float* __restrict__ x,     // [chunk,3,1024]
    const float* __restrict__ w1p,   // [256][4] f32: w0,w1,w2,b1
    const u16* __restrict__ W2b,     // [256,256] bf16
    const float* __restrict__ b2,    // [256]
    const float* __restrict__ r,     // [1024]
    const int* __restrict__ nbi, const float* __restrict__ nbc,
    u16* __restrict__ C)             // h2 [M,256] bf16
{
  const int K = 256;
  __shared__ u16 As[128 * 64];       // 16 KB (swizzled)
  __shared__ u16 Bs[256 * 64];       // 32 KB (glds source-swizzled)
  __shared__ u16 h1c[192 * 64];      // 24 KB (swizzled)
  __shared__ float gxs[192][4];      // 3 KB  (gx0,gx1,gx2,rn) per halo node

  int m0 = blockIdx.x * 128;
  int b = m0 >> 10;
  int node0 = m0 & 1023;
  int e0 = node0 - 32;
  int tid = threadIdx.x;
  int w = tid >> 6, l = tid & 63;
  int wm = w >> 1, wn = w & 1;

  // B staging (proven swizzled-glds layout)
  int r8 = l >> 3, oct = l & 7;
  int so = (oct ^ r8) << 3;
  const u16* gb0 = W2b + (size_t)(w * 64 + r8) * K + so;

#define L12_ISSUEB(kq) \
  _Pragma("unroll") for (int q = 0; q < 8; q++) \
    async_copy16(gb0 + (size_t)q * 8 * K + (kq) * 64, &Bs[(w * 64 + q * 8) * 64]);

  L12_ISSUEB(0);

  // prologue: halo gx
  if (tid < 192) {
    int n = e0 + tid;
    float4 gv = {0.f, 0.f, 0.f, 0.f};
    if (n >= 0 && n < N_NODES) {
      const float* xb = x + (size_t)b * 3072;
      float g0 = 0.f, g1 = 0.f, g2 = 0.f;
#pragma unroll
      for (int t = 0; t < 5; t++) {
        int nb = nbi[n * 5 + t]; float cv = nbc[n * 5 + t];
        g0 += cv * xb[nb];
        g1 += cv * xb[1024 + nb];
        g2 += cv * xb[2048 + nb];
      }
      gv.x = g0; gv.y = g1; gv.z = g2; gv.w = r[n];
    }
    *(float4*)&gxs[tid][0] = gv;
  }

  // phase-1 assignment: thread -> (8-ch octet cg, rows rb, rb+32, ..., rb+160)
  int cg = tid & 7;
  int rb = tid >> 3;                 // 0..31

  // Two jh halves of the octet -> only 16 coef regs live at a time (q[4]).
#define L12_PHASE1(kq_) { \
    _Pragma("unroll") for (int jh = 0; jh < 2; jh++) { \
      float4 q_[4]; \
      _Pragma("unroll") for (int j = 0; j < 4; j++) \
        q_[j] = ((const float4*)w1p)[(kq_) * 64 + cg * 8 + jh * 4 + j]; \
      _Pragma("unroll") for (int i = 0; i < 6; i++) { \
        int row_ = rb + 32 * i; \
        float4 g_ = *(const float4*)&gxs[row_][0]; \
        float h_[4]; \
        _Pragma("unroll") for (int j = 0; j < 4; j++) \
          h_[j] = fmaxf(fmaf(g_.x, q_[j].x, fmaf(g_.y, q_[j].y, fmaf(g_.z, q_[j].z, g_.w * q_[j].w))), 0.f); \
        uint32_t pk_[2]; \
        pk_[0] = pkbf(h_[0], h_[1]); pk_[1] = pkbf(h_[2], h_[3]); \
        *(uint2*)&h1c[row_ * 64 + ((cg ^ (row_ & 7)) << 3) + jh * 4] = *(uint2*)pk_; \
      } \
    } }

  // phase-2 assignment: thread -> (out row arow, 32-ch half lo0)
  int arow = tid >> 1;
  int lo0 = (tid & 1) << 2;          // logical octet base 0/4
  int node = node0 + arow;
  int pidx[5]; float pcf[5];
#pragma unroll
  for (int t = 0; t < 5; t++) {
    pidx[t] = nbi[node * 5 + t] - e0;    // always in [0,192)
    pcf[t]  = nbc[node * 5 + t];
  }
  int asw = arow & 7;

#define L12_PHASE2() \
  _Pragma("unroll") for (int q = 0; q < 4; q++) { \
    int lo_ = lo0 + q; \
    float2 a2_[4] = {}; \
    _Pragma("unroll") for (int t = 0; t < 5; t++) { \
      int id_ = pidx[t]; \
      uint4 v_ = *(const uint4*)&h1c[id_ * 64 + ((lo_ ^ (id_ & 7)) << 3)]; \
      agg8(v_, pcf[t], a2_); \
    } \
    uint4 o_; \
    o_.x = pkbf(a2_[0].x, a2_[0].y); o_.y = pkbf(a2_[1].x, a2_[1].y); \
    o_.z = pkbf(a2_[2].x, a2_[2].y); o_.w = pkbf(a2_[3].x, a2_[3].y); \
    *(uint4*)&As[arow * 64 + ((lo_ ^ asw) << 3)] = o_; \
  }

  __syncthreads();        // gxs ready
  L12_PHASE1(0);

  f32x4 acc[4][8] = {};
  int lrow = l & 15, lq = l >> 4;
  int s2 = lrow & 7;

  for (int kq = 0; kq < 4; kq++) {
    __syncthreads();            // (A) h1c(kq) visible; prev MFMA done (As/Bs free)
    if (kq) L12_ISSUEB(kq);     // W2 chunk kq in flight under phase2
    L12_PHASE2();               // h1c(kq) -> As
    __syncthreads();            // (B) As ready; Bs(kq) glds drained
    if (kq < 3) L12_PHASE1(kq + 1);   // co-scheduled with MFMA below

    const u16* pa = &As[(wm * 64 + lrow) * 64];
    const u16* pb = &Bs[(wn * 128 + lrow) * 64];
#pragma unroll
    for (int kh = 0; kh < 2; kh++) {
      int po = (((kh << 2) | lq) ^ s2) << 3;   // physical octet offset (A and B)
      bf16x8 af[4], bf[8];
#pragma unroll
      for (int t = 0; t < 4; t++)
        af[t] = *(const bf16x8*)(pa + t * 16 * 64 + po);
#pragma unroll
      for (int t = 0; t < 8; t++)
        bf[t] = *(const bf16x8*)(pb + t * 16 * 64 + po);
#pragma unroll
      for (int mt = 0; mt < 4; mt++)
#pragma unroll
        for (int nt = 0; nt < 8; nt++)
          acc[mt][nt] = __builtin_amdgcn_mfma_f32_16x16x32_bf16(af[mt], bf[nt], acc[mt][nt], 0, 0, 0);
    }
  }
#undef L12_ISSUEB
#undef L12_PHASE1
#undef L12_PHASE2

#pragma unroll
  for (int mt = 0; mt < 4; mt++)
#pragma unroll
    for (int nt = 0; nt < 8; nt++) {
      f32x4 v = acc[mt][nt];
      int col = wn * 128 + nt * 16 + lrow;
      float bs = b2[col];
#pragma unroll
      for (int i2 = 0; i2 < 4; i2++) {
        int row = m0 + wm * 64 + mt * 16 + lq * 4 + i2;
        float val = v[i2] + r[row & 1023] * bs;
        C[(size_t)row * 256 + col] = f2b(fmaxf(val, 0.f));
      }
    }
}

// ---------------- mm3agg + MFMA classifier ----------------
// h3 = relu((A h2) W3^T + r.b3) -> LDS tile (never HBM); classifier done as
// 512 MFMAs/block: A = h3 flat-k broadcast (16 identical rows — MFMA pipe is
// idle anyway), B = Wcf fragment (lane&15 = class, contiguous 16 B per lane
// per step). Each lane's D value is the complete k-sum for its class; one
// LDS write per wave + one atomicAdd per block.
__global__ __launch_bounds__(256, 2) void mm3agg_kernel(
    const u16* __restrict__ H,      // h2 [chunk*1024, 256]
    const u16* __restrict__ W,      // W3b [128, 256]
    const float* __restrict__ bias, const float* __restrict__ r,
    const int* __restrict__ nbi, const float* __restrict__ nbc,
    const u16* __restrict__ Wcf,    // [KDIM/32][64][8] bf16 B-frag layout
    float* __restrict__ out,        // [256,10] f32 (pre-initialized to bc)
    int b0)
{
  const int K = 256;
  const int AST = 72;               // padded A row stride (elements)
  __shared__ u16 As[2][128 * AST];  // 2x18 KB (reused as 32 KB h3 tile after K-loop)
  __shared__ u16 Bs[2][128 * 64];   // 2x16 KB
  __shared__ float cred[4][NCLS];
  int m0 = blockIdx.x * 128;
  int tid = threadIdx.x;
  int w = tid >> 6, l = tid & 63;
  int wm = w >> 1, wn = w & 1;

  // aggregation: thread -> (row = tid/2, 32-col half of each 64-k chunk)
  int arow = tid >> 1;
  int acol = (tid & 1) * 32;
  int pg = m0 + arow;
  int node = pg & 1023;
  const u16* hb = H + ((size_t)(pg >> 10) << 10) * 256 + acol;
  const u16* nbp[5]; float cf[5];
#pragma unroll
  for (int j = 0; j < 5; j++) {
    nbp[j] = hb + (size_t)nbi[node * 5 + j] * 256;
    cf[j] = nbc[node * 5 + j];
  }

  // B staging
  int r8 = l >> 3, oct = l & 7;
  int so = (oct ^ r8) << 3;
  const u16* gb0 = W + (size_t)(w * 32 + r8) * K + so;

#define M3_ISSUEB(kq, buf) \
  _Pragma("unroll") for (int q = 0; q < 4; q++) \
    async_copy16(gb0 + (size_t)q * 8 * K + (kq) * 64, &Bs[buf][(w * 32 + q * 8) * 64]);

#define M3_LOADA(kq) \
  _Pragma("unroll") for (int j = 0; j < 5; j++) \
    _Pragma("unroll") for (int q = 0; q < 4; q++) \
      L[j][q] = *(const uint4*)(nbp[j] + (kq) * 64 + q * 8);

#define M3_AGGSTORE(buf) { \
  u16* dst = &As[buf][arow * AST + acol]; \
  _Pragma("unroll") for (int q = 0; q < 4; q++) { \
    float2 acc2[4] = {}; \
    _Pragma("unroll") for (int j = 0; j < 5; j++) agg8(L[j][q], cf[j], acc2); \
    uint4 o; \
    o.x = pkbf(acc2[0].x, acc2[0].y); o.y = pkbf(acc2[1].x, acc2[1].y); \
    o.z = pkbf(acc2[2].x, acc2[2].y); o.w = pkbf(acc2[3].x, acc2[3].y); \
    *(uint4*)(dst + q * 8) = o; \
  } }

  uint4 L[5][4];
  M3_ISSUEB(0, 0);
  M3_LOADA(0);
  M3_AGGSTORE(0);

  f32x4 acc[4][4] = {};
  int lrow = l & 15, lq = l >> 4;
  int s = lrow & 7;

#pragma unroll
  for (int kq = 0; kq < 4; kq++) {
    int buf = kq & 1;
    __syncthreads();
    if (kq < 3) {
      M3_ISSUEB(kq + 1, buf ^ 1);
      M3_LOADA(kq + 1);               // in flight during MFMA below
    }
    const u16* pa = &As[buf][(wm * 64 + lrow) * AST];
    const u16* pb = &Bs[buf][(wn * 64 + lrow) * 64];
#pragma unroll
    for (int kh = 0; kh < 2; kh++) {
      int po = (((kh << 2) | lq) ^ s) << 3;
      bf16x8 af[4], bf[4];
#pragma unroll
      for (int t = 0; t < 4; t++) {
        af[t] = *(const bf16x8*)(pa + t * 16 * AST + kh * 32 + lq * 8);
        bf[t] = *(const bf16x8*)(pb + t * 16 * 64 + po);
      }
#pragma unroll
      for (int mt = 0; mt < 4; mt++)
#pragma unroll
        for (int nt = 0; nt < 4; nt++)
          acc[mt][nt] = __builtin_amdgcn_mfma_f32_16x16x32_bf16(af[mt], bf[nt], acc[mt][nt], 0, 0, 0);
    }
    if (kq < 3) M3_AGGSTORE(buf ^ 1);
  }
#undef M3_ISSUEB
#undef M3_LOADA
#undef M3_AGGSTORE

  // ---- epilogue: h3 -> LDS tile, classifier via MFMA ----
  __syncthreads();                 // K-loop reads of As/Bs done
  u16* h3s = (u16*)As;             // [128][128] bf16 = 32 KB
#pragma unroll
  for (int mt = 0; mt < 4; mt++)
#pragma unroll
    for (int nt = 0; nt < 4; nt++) {
      f32x4 v = acc[mt][nt];
      int col = wn * 64 + nt * 16 + lrow;
      float bs = bias[col];
#pragma unroll
      for (int i2 = 0; i2 < 4; i2++) {
        int lr = wm * 64 + mt * 16 + lq * 4 + i2;
        float h = fmaxf(v[i2] + r[(m0 + lr) & 1023] * bs, 0.f);
        h3s[lr * 128 + col] = f2b(h);
      }
    }
  __syncthreads();                 // h3 tile visible

  // wave w covers local kb in [w*128, w*128+128); global kb = node0*4 + kb
  int node0 = m0 & 1023;
  const u16* wp = Wcf + ((size_t)(node0 * 4 + w * 128) * 64 + l) * 8;
  const u16* ap = h3s + w * 128 * 32 + lq * 8;
  f32x4 cacc = {};
#pragma unroll 8
  for (int t = 0; t < 128; t++) {
    bf16x8 bfv = *(const bf16x8*)(wp + (size_t)t * 512);  // 16 B coalesced, L2
    bf16x8 afv = *(const bf16x8*)(ap + t * 32);           // LDS broadcast
    cacc = __builtin_amdgcn_mfma_f32_16x16x32_bf16(afv, bfv, cacc, 0, 0, 0);
  }
  if (l < NCLS) cred[w][l] = cacc[0];   // col = l = class; full k-sum per lane
  __syncthreads();
  if (tid < NCLS) {
    int bimg = b0 + (m0 >> 10);
    atomicAdd(&out[bimg * NCLS + tid],
              cred[0][tid] + cred[1][tid] + cred[2][tid] + cred[3][tid]);
  }
}

extern "C" void kernel_launch(void* const* d_in, const int* in_sizes, int n_in,
                              void* d_out, int out_size, void* d_ws, size_t ws_size,
                              hipStream_t stream) {
  const float* x   = (const float*)d_in[0];
  const float* W1  = (const float*)d_in[1];
  const float* b1  = (const float*)d_in[2];
  const float* W2  = (const float*)d_in[3];
  const float* b2  = (const float*)d_in[4];
  const float* W3  = (const float*)d_in[5];
  const float* b3  = (const float*)d_in[6];
  const float* Wc  = (const float*)d_in[7];
  const float* bc  = (const float*)d_in[8];
  const float* adj = (const float*)d_in[9];
  float* out = (float*)d_out;
  const int B = 256;

  uint8_t* ws = (uint8_t*)d_ws;
  u16* W2b = (u16*)ws;  ws += (size_t)256 * 256 * 2;
  u16* W3b = (u16*)ws;  ws += (size_t)128 * 256 * 2;
  u16* Wcf = (u16*)ws;  ws += (size_t)KDIM * 16 * 2;
  float* rr  = (float*)ws; ws += 1024 * 4;
  int*   nbi = (int*)ws;   ws += 1024 * 5 * 4;
  float* nbc = (float*)ws; ws += 1024 * 5 * 4;
  float* w1p = (float*)ws; ws += 256 * 4 * 4;
  uintptr_t al = ((uintptr_t)ws + 255) & ~(uintptr_t)255;
  ws = (uint8_t*)al;
  size_t used = (size_t)(ws - (uint8_t*)d_ws);
  size_t avail = (ws_size > used) ? ws_size - used : 0;
  int chunk = 256;
  while (chunk > 32 && (size_t)chunk * 1024 * 256 * 2 > avail) chunk >>= 1;
  u16* bufA = (u16*)ws;   // h2 only; h3 is never materialized

  prep_all_kernel<<<PREP_GRID, 256, 0, stream>>>(W2, W3, Wc, W1, b1, bc, adj,
                                                 W2b, W3b, Wcf, w1p, nbi, nbc, rr, out);

  for (int b0 = 0; b0 < B; b0 += chunk) {
    const float* xb = x + (size_t)b0 * 3 * 1024;
    int M = chunk * 1024;
    // h2 = relu((A.h1) W2^T + r.b2) fused from x -> bufA
    l12mm_kernel<<<M / 128, 256, 0, stream>>>(xb, w1p, W2b, b2, rr, nbi, nbc, bufA);
    // h3 = relu((A.h2) W3^T + r.b3) in-reg/LDS, classifier via MFMA
    mm3agg_kernel<<<M / 128, 256, 0, stream>>>(bufA, W3b, b3, rr, nbi, nbc, Wcf, out, b0);
  }
}